// Round 1
// baseline (711.218 us; speedup 1.0000x reference)
//
#include <hip/hip_runtime.h>
#include <math.h>

#define BB 8
#define CC 256
#define NN 2048
static constexpr float BN_EPS = 1e-5f;

// ---------------------------------------------------------------------------
// Tiled fp32 GEMM building blocks: 64x64 output tile, K-step 16, 256 threads,
// each thread computes a 4x4 register tile.
// ---------------------------------------------------------------------------

// Kernel 1: projections Q = Wq*X, K = Wk*X, V = Wv*X + bv  (per batch b)
// W is [C_out, C_in] row-major, X is [C, N]; output [C, N].
__global__ __launch_bounds__(256) void proj_kernel(
    const float* __restrict__ x, const float* __restrict__ Wq,
    const float* __restrict__ Wk, const float* __restrict__ Wv,
    const float* __restrict__ bv,
    float* __restrict__ Q, float* __restrict__ Kout, float* __restrict__ V)
{
    const int which = blockIdx.z / BB;   // 0=Q,1=K,2=V
    const int b     = blockIdx.z % BB;
    const float* __restrict__ W = (which == 0) ? Wq : (which == 1) ? Wk : Wv;
    float* __restrict__ O       = (which == 0) ? Q  : (which == 1) ? Kout : V;
    const float* __restrict__ Xb = x + (size_t)b * CC * NN;
    float* __restrict__ Ob       = O + (size_t)b * CC * NN;

    const int m0 = blockIdx.y * 64;   // output channel tile
    const int n0 = blockIdx.x * 64;   // point tile
    const int tid = threadIdx.x;
    const int tm = tid >> 4, tn = tid & 15;

    __shared__ float As[16][68];   // As[k][m] = W[m0+m][k0+k] (transposed, padded)
    __shared__ float Bs[16][64];   // Bs[k][n] = X[k0+k][n0+n]

    float acc[4][4] = {};

    for (int k0 = 0; k0 < CC; k0 += 16) {
#pragma unroll
        for (int i = 0; i < 4; ++i) {
            int idx = tid + 256 * i;
            int m = idx >> 4, k = idx & 15;
            As[k][m] = W[(size_t)(m0 + m) * CC + k0 + k];
        }
#pragma unroll
        for (int i = 0; i < 4; ++i) {
            int idx = tid + 256 * i;
            int k = idx >> 6, n = idx & 63;
            Bs[k][n] = Xb[(size_t)(k0 + k) * NN + n0 + n];
        }
        __syncthreads();
#pragma unroll
        for (int k = 0; k < 16; ++k) {
            float4 a4 = *(const float4*)&As[k][tm * 4];
            float4 b4 = *(const float4*)&Bs[k][tn * 4];
            float av[4] = {a4.x, a4.y, a4.z, a4.w};
            float bw[4] = {b4.x, b4.y, b4.z, b4.w};
#pragma unroll
            for (int i = 0; i < 4; ++i)
#pragma unroll
                for (int j = 0; j < 4; ++j) acc[i][j] += av[i] * bw[j];
        }
        __syncthreads();
    }

#pragma unroll
    for (int i = 0; i < 4; ++i) {
        int row = m0 + tm * 4 + i;
        float bb = (which == 2) ? bv[row] : 0.f;
        float4 o;
        o.x = acc[i][0] + bb; o.y = acc[i][1] + bb;
        o.z = acc[i][2] + bb; o.w = acc[i][3] + bb;
        *(float4*)&Ob[(size_t)row * NN + n0 + tn * 4] = o;
    }
}

// Kernel 2: energy[b,n,m] = sum_c Q[b,c,n] * K[b,c,m]   -> ATT (raw logits)
__global__ __launch_bounds__(256) void energy_kernel(
    const float* __restrict__ Q, const float* __restrict__ Kin,
    float* __restrict__ ATT)
{
    const int b = blockIdx.z;
    const float* __restrict__ Qb = Q   + (size_t)b * CC * NN;
    const float* __restrict__ Kb = Kin + (size_t)b * CC * NN;
    float* __restrict__ Eb       = ATT + (size_t)b * NN * NN;

    const int r0 = blockIdx.y * 64;   // n rows (from Q)
    const int c0 = blockIdx.x * 64;   // m cols (from K)
    const int tid = threadIdx.x;
    const int tm = tid >> 4, tn = tid & 15;

    __shared__ float As[16][64];   // As[k][r] = Q[k0+k][r0+r]
    __shared__ float Bs[16][64];   // Bs[k][c] = K[k0+k][c0+c]

    float acc[4][4] = {};

    for (int k0 = 0; k0 < CC; k0 += 16) {
#pragma unroll
        for (int i = 0; i < 4; ++i) {
            int idx = tid + 256 * i;
            int k = idx >> 6, n = idx & 63;
            As[k][n] = Qb[(size_t)(k0 + k) * NN + r0 + n];
            Bs[k][n] = Kb[(size_t)(k0 + k) * NN + c0 + n];
        }
        __syncthreads();
#pragma unroll
        for (int k = 0; k < 16; ++k) {
            float4 a4 = *(const float4*)&As[k][tm * 4];
            float4 b4 = *(const float4*)&Bs[k][tn * 4];
            float av[4] = {a4.x, a4.y, a4.z, a4.w};
            float bw[4] = {b4.x, b4.y, b4.z, b4.w};
#pragma unroll
            for (int i = 0; i < 4; ++i)
#pragma unroll
                for (int j = 0; j < 4; ++j) acc[i][j] += av[i] * bw[j];
        }
        __syncthreads();
    }

#pragma unroll
    for (int i = 0; i < 4; ++i) {
        int row = r0 + tm * 4 + i;
        *(float4*)&Eb[(size_t)row * NN + c0 + tn * 4] =
            make_float4(acc[i][0], acc[i][1], acc[i][2], acc[i][3]);
    }
}

// Kernel 3: in-place row softmax over last axis (m). One block per (b,n) row.
__global__ __launch_bounds__(256) void softmax_kernel(float* __restrict__ ATT)
{
    const size_t row = blockIdx.x;           // b*NN + n
    float* __restrict__ R = ATT + row * NN;
    const int tid = threadIdx.x;
    const int wave = tid >> 6, lane = tid & 63;

    float e[8];
#pragma unroll
    for (int j = 0; j < 8; ++j) e[j] = R[tid + 256 * j];

    float mx = e[0];
#pragma unroll
    for (int j = 1; j < 8; ++j) mx = fmaxf(mx, e[j]);
#pragma unroll
    for (int s = 1; s < 64; s <<= 1) mx = fmaxf(mx, __shfl_xor(mx, s));

    __shared__ float redm[4];
    if (lane == 0) redm[wave] = mx;
    __syncthreads();
    mx = fmaxf(fmaxf(redm[0], redm[1]), fmaxf(redm[2], redm[3]));

    float s = 0.f;
#pragma unroll
    for (int j = 0; j < 8; ++j) { e[j] = __expf(e[j] - mx); s += e[j]; }
#pragma unroll
    for (int t = 1; t < 64; t <<= 1) s += __shfl_xor(s, t);

    __shared__ float reds[4];
    if (lane == 0) reds[wave] = s;
    __syncthreads();
    s = reds[0] + reds[1] + reds[2] + reds[3];

    const float inv = 1.f / s;
#pragma unroll
    for (int j = 0; j < 8; ++j) R[tid + 256 * j] = e[j] * inv;
}

// Kernel 4: column sums colsum[b,m] = sum_n ATT[b,n,m] (partial chunks+atomics)
__global__ __launch_bounds__(256) void colsum_kernel(
    const float* __restrict__ ATT, float* __restrict__ colsum)
{
    const int b = blockIdx.z;
    const int m = blockIdx.x * 256 + threadIdx.x;
    const int n0 = blockIdx.y * 128;
    const float* __restrict__ Ab = ATT + (size_t)b * NN * NN;
    float s = 0.f;
    for (int n = n0; n < n0 + 128; ++n) s += Ab[(size_t)n * NN + m];
    atomicAdd(&colsum[b * NN + m], s);
}

// Kernel 5: R = V * (ATT * diag(1/(1e-9+colsum))); write D = x - R (into Q buf)
__global__ __launch_bounds__(256) void xr_kernel(
    const float* __restrict__ V, const float* __restrict__ ATT,
    const float* __restrict__ colsum, const float* __restrict__ x,
    float* __restrict__ D)
{
    const int b = blockIdx.z;
    const int r0 = blockIdx.y * 64;   // channel tile (CC/64 = 4)
    const int c0 = blockIdx.x * 64;   // point tile m
    const float* __restrict__ Vb = V   + (size_t)b * CC * NN;
    const float* __restrict__ Ab = ATT + (size_t)b * NN * NN;
    const float* __restrict__ Xb = x   + (size_t)b * CC * NN;
    float* __restrict__ Db       = D   + (size_t)b * CC * NN;

    const int tid = threadIdx.x;
    const int tm = tid >> 4, tn = tid & 15;

    // per-thread column scale: loader column c = tid & 63 (invariant mod 64)
    const float rcv = 1.f / (1e-9f + colsum[b * NN + c0 + (tid & 63)]);

    __shared__ float As[16][68];   // As[k][r] = V[r0+r][k0+k] (transposed)
    __shared__ float Bs[16][64];   // Bs[k][c] = ATT[k0+k][c0+c] * rc[c]

    float acc[4][4] = {};

    for (int k0 = 0; k0 < NN; k0 += 16) {
#pragma unroll
        for (int i = 0; i < 4; ++i) {
            int idx = tid + 256 * i;
            int r = idx >> 4, k = idx & 15;
            As[k][r] = Vb[(size_t)(r0 + r) * NN + k0 + k];
        }
#pragma unroll
        for (int i = 0; i < 4; ++i) {
            int idx = tid + 256 * i;
            int k = idx >> 6, c = idx & 63;
            Bs[k][c] = Ab[(size_t)(k0 + k) * NN + c0 + c] * rcv;
        }
        __syncthreads();
#pragma unroll
        for (int k = 0; k < 16; ++k) {
            float4 a4 = *(const float4*)&As[k][tm * 4];
            float4 b4 = *(const float4*)&Bs[k][tn * 4];
            float av[4] = {a4.x, a4.y, a4.z, a4.w};
            float bw[4] = {b4.x, b4.y, b4.z, b4.w};
#pragma unroll
            for (int i = 0; i < 4; ++i)
#pragma unroll
                for (int j = 0; j < 4; ++j) acc[i][j] += av[i] * bw[j];
        }
        __syncthreads();
    }

#pragma unroll
    for (int i = 0; i < 4; ++i) {
        int row = r0 + tm * 4 + i;
        float4 xv = *(const float4*)&Xb[(size_t)row * NN + c0 + tn * 4];
        float4 o;
        o.x = xv.x - acc[i][0]; o.y = xv.y - acc[i][1];
        o.z = xv.z - acc[i][2]; o.w = xv.w - acc[i][3];
        *(float4*)&Db[(size_t)row * NN + c0 + tn * 4] = o;
    }
}

// Kernel 6: XZ = alpha*(Wt*D + bt) + beta; accumulate BN sums per channel.
__global__ __launch_bounds__(256) void xz_kernel(
    const float* __restrict__ Wt, const float* __restrict__ D,
    const float* __restrict__ bt, const float* __restrict__ alpha,
    const float* __restrict__ beta, float* __restrict__ XZ,
    float* __restrict__ bnsum, float* __restrict__ bnsumsq)
{
    const int b = blockIdx.z;
    const int m0 = blockIdx.y * 64;
    const int n0 = blockIdx.x * 64;
    const float* __restrict__ Db = D  + (size_t)b * CC * NN;
    float* __restrict__ Zb       = XZ + (size_t)b * CC * NN;

    const int tid = threadIdx.x;
    const int tm = tid >> 4, tn = tid & 15;

    __shared__ float As[16][68];
    __shared__ float Bs[16][64];

    float acc[4][4] = {};

    for (int k0 = 0; k0 < CC; k0 += 16) {
#pragma unroll
        for (int i = 0; i < 4; ++i) {
            int idx = tid + 256 * i;
            int m = idx >> 4, k = idx & 15;
            As[k][m] = Wt[(size_t)(m0 + m) * CC + k0 + k];
        }
#pragma unroll
        for (int i = 0; i < 4; ++i) {
            int idx = tid + 256 * i;
            int k = idx >> 6, n = idx & 63;
            Bs[k][n] = Db[(size_t)(k0 + k) * NN + n0 + n];
        }
        __syncthreads();
#pragma unroll
        for (int k = 0; k < 16; ++k) {
            float4 a4 = *(const float4*)&As[k][tm * 4];
            float4 b4 = *(const float4*)&Bs[k][tn * 4];
            float av[4] = {a4.x, a4.y, a4.z, a4.w};
            float bw[4] = {b4.x, b4.y, b4.z, b4.w};
#pragma unroll
            for (int i = 0; i < 4; ++i)
#pragma unroll
                for (int j = 0; j < 4; ++j) acc[i][j] += av[i] * bw[j];
        }
        __syncthreads();
    }

#pragma unroll
    for (int i = 0; i < 4; ++i) {
        int row = m0 + tm * 4 + i;
        const float al = alpha[row], be = beta[row], bb = bt[row];
        float4 z;
        z.x = al * (acc[i][0] + bb) + be;
        z.y = al * (acc[i][1] + bb) + be;
        z.z = al * (acc[i][2] + bb) + be;
        z.w = al * (acc[i][3] + bb) + be;
        *(float4*)&Zb[(size_t)row * NN + n0 + tn * 4] = z;

        float ps  = z.x + z.y + z.z + z.w;
        float ps2 = z.x * z.x + z.y * z.y + z.z * z.z + z.w * z.w;
#pragma unroll
        for (int s = 1; s < 16; s <<= 1) {
            ps  += __shfl_xor(ps, s);
            ps2 += __shfl_xor(ps2, s);
        }
        if (tn == 0) {
            atomicAdd(&bnsum[row], ps);
            atomicAdd(&bnsumsq[row], ps2);
        }
    }
}

// Kernel 7: out = x + relu(gamma*(XZ-mean)*rsqrt(var+eps)+beta)
__global__ __launch_bounds__(256) void final_kernel(
    const float* __restrict__ x, const float* __restrict__ XZ,
    const float* __restrict__ bnsum, const float* __restrict__ bnsumsq,
    const float* __restrict__ gamma, const float* __restrict__ bbeta,
    float* __restrict__ out)
{
    const int i4 = blockIdx.x * 256 + threadIdx.x;   // float4 index
    const int elem = i4 * 4;
    const int c = (elem / NN) % CC;
    const float inv_cnt = 1.f / (float)(BB * NN);
    const float mean = bnsum[c] * inv_cnt;
    const float var  = bnsumsq[c] * inv_cnt - mean * mean;
    const float rs = rsqrtf(var + BN_EPS);
    const float g = gamma[c], bb = bbeta[c];

    float4 z = *(const float4*)&XZ[elem];
    float4 xv = *(const float4*)&x[elem];
    float4 o;
    o.x = xv.x + fmaxf(g * (z.x - mean) * rs + bb, 0.f);
    o.y = xv.y + fmaxf(g * (z.y - mean) * rs + bb, 0.f);
    o.z = xv.z + fmaxf(g * (z.z - mean) * rs + bb, 0.f);
    o.w = xv.w + fmaxf(g * (z.w - mean) * rs + bb, 0.f);
    *(float4*)&out[elem] = o;
}

// ---------------------------------------------------------------------------

extern "C" void kernel_launch(void* const* d_in, const int* in_sizes, int n_in,
                              void* d_out, int out_size, void* d_ws, size_t ws_size,
                              hipStream_t stream) {
    const float* x     = (const float*)d_in[0];
    const float* Wq    = (const float*)d_in[1];
    const float* Wk    = (const float*)d_in[2];
    const float* Wv    = (const float*)d_in[3];
    const float* bv    = (const float*)d_in[4];
    const float* Wt    = (const float*)d_in[5];
    const float* bt    = (const float*)d_in[6];
    const float* gamma = (const float*)d_in[7];
    const float* bbeta = (const float*)d_in[8];
    const float* alpha = (const float*)d_in[9];
    const float* beta  = (const float*)d_in[10];
    float* out = (float*)d_out;

    float* ws = (float*)d_ws;
    const size_t BCN = (size_t)BB * CC * NN;        // 4,194,304
    float* Q      = ws;
    float* K      = ws + BCN;
    float* V      = ws + 2 * BCN;
    float* ATT    = ws + 3 * BCN;                    // B*N*N floats
    float* XZ     = ATT + (size_t)BB * NN * NN;
    float* colsum = XZ + BCN;                        // B*N
    float* bnsum  = colsum + (size_t)BB * NN;        // C
    float* bnsumsq = bnsum + CC;                     // C
    float* D      = Q;                               // reuse Q after energy

    // zero accumulators (colsum | bnsum | bnsumsq are contiguous)
    hipMemsetAsync(colsum, 0, (size_t)(BB * NN + 2 * CC) * sizeof(float), stream);

    proj_kernel<<<dim3(NN / 64, CC / 64, 3 * BB), 256, 0, stream>>>(
        x, Wq, Wk, Wv, bv, Q, K, V);
    energy_kernel<<<dim3(NN / 64, NN / 64, BB), 256, 0, stream>>>(Q, K, ATT);
    softmax_kernel<<<dim3(BB * NN), 256, 0, stream>>>(ATT);
    colsum_kernel<<<dim3(NN / 256, 16, BB), 256, 0, stream>>>(ATT, colsum);
    xr_kernel<<<dim3(NN / 64, CC / 64, BB), 256, 0, stream>>>(V, ATT, colsum, x, D);
    xz_kernel<<<dim3(NN / 64, CC / 64, BB), 256, 0, stream>>>(
        Wt, D, bt, alpha, beta, XZ, bnsum, bnsumsq);
    final_kernel<<<dim3((int)(BCN / 4 / 256)), 256, 0, stream>>>(
        x, XZ, bnsum, bnsumsq, gamma, bbeta, out);
}

// Round 2
// 341.425 us; speedup vs baseline: 2.0831x; 2.0831x over previous
//
#include <hip/hip_runtime.h>
#include <math.h>

#define BB 8
#define CC 256
#define NN 2048
static constexpr float BN_EPS = 1e-5f;

typedef _Float16 f16;
typedef f16 f16x2 __attribute__((ext_vector_type(2)));
typedef f16 f16x4 __attribute__((ext_vector_type(4)));
typedef f16 f16x8 __attribute__((ext_vector_type(8)));
typedef float f32x4 __attribute__((ext_vector_type(4)));

// ---------------------------------------------------------------------------
// Kernel 1: projections. Q^T,K^T written as [B][N][C]; V as [B][C][N] + bv.
// fp32 tiled GEMM, 64x64 tile, 256 threads, 4x4 per thread.
// ---------------------------------------------------------------------------
__global__ __launch_bounds__(256) void proj_kernel(
    const float* __restrict__ x, const float* __restrict__ Wq,
    const float* __restrict__ Wk, const float* __restrict__ Wv,
    const float* __restrict__ bv,
    float* __restrict__ Qt, float* __restrict__ Kt, float* __restrict__ V)
{
    const int which = blockIdx.z / BB;   // 0=Q,1=K,2=V
    const int b     = blockIdx.z % BB;
    const float* __restrict__ W = (which == 0) ? Wq : (which == 1) ? Wk : Wv;
    const float* __restrict__ Xb = x + (size_t)b * CC * NN;

    const int m0 = blockIdx.y * 64;   // output channel tile
    const int n0 = blockIdx.x * 64;   // point tile
    const int tid = threadIdx.x;
    const int tm = tid >> 4, tn = tid & 15;

    __shared__ float As[16][68];   // As[k][m] = W[m0+m][k0+k]
    __shared__ float Bs[16][64];   // Bs[k][n] = X[k0+k][n0+n]
    __shared__ float T[64][68];    // transpose staging for Q/K epilogue

    float acc[4][4] = {};

    for (int k0 = 0; k0 < CC; k0 += 16) {
#pragma unroll
        for (int i = 0; i < 4; ++i) {
            int idx = tid + 256 * i;
            int m = idx >> 4, k = idx & 15;
            As[k][m] = W[(size_t)(m0 + m) * CC + k0 + k];
        }
#pragma unroll
        for (int i = 0; i < 4; ++i) {
            int idx = tid + 256 * i;
            int k = idx >> 6, n = idx & 63;
            Bs[k][n] = Xb[(size_t)(k0 + k) * NN + n0 + n];
        }
        __syncthreads();
#pragma unroll
        for (int k = 0; k < 16; ++k) {
            float4 a4 = *(const float4*)&As[k][tm * 4];
            float4 b4 = *(const float4*)&Bs[k][tn * 4];
            float av[4] = {a4.x, a4.y, a4.z, a4.w};
            float bw[4] = {b4.x, b4.y, b4.z, b4.w};
#pragma unroll
            for (int i = 0; i < 4; ++i)
#pragma unroll
                for (int j = 0; j < 4; ++j) acc[i][j] += av[i] * bw[j];
        }
        __syncthreads();
    }

    if (which == 2) {
        float* __restrict__ Ob = V + (size_t)b * CC * NN;
#pragma unroll
        for (int i = 0; i < 4; ++i) {
            int row = m0 + tm * 4 + i;
            float bb = bv[row];
            float4 o;
            o.x = acc[i][0] + bb; o.y = acc[i][1] + bb;
            o.z = acc[i][2] + bb; o.w = acc[i][3] + bb;
            *(float4*)&Ob[(size_t)row * NN + n0 + tn * 4] = o;
        }
    } else {
        // transposed write: Ot[n][c], via LDS so global writes stay coalesced
        float* __restrict__ Ot = ((which == 0) ? Qt : Kt) + (size_t)b * NN * CC;
#pragma unroll
        for (int i = 0; i < 4; ++i)
#pragma unroll
            for (int j = 0; j < 4; ++j) T[tn * 4 + j][tm * 4 + i] = acc[i][j];
        __syncthreads();
#pragma unroll
        for (int ii = 0; ii < 4; ++ii) {
            int idx = tid + 256 * ii;
            int nl = idx >> 4;            // 0..63
            int cl = (idx & 15) * 4;      // 0..60
            float4 o = *(float4*)&T[nl][cl];
            *(float4*)&Ot[(size_t)(n0 + nl) * CC + m0 + cl] = o;
        }
    }
}

// ---------------------------------------------------------------------------
// Kernel 2: energy[b,n,m] = sum_c Qt[b,n,c] * Kt[b,m,c]  (MFMA f16)
// 128x128 tile, 4 waves, each wave 64x64 = 4x4 fragments of 16x16x32.
// ---------------------------------------------------------------------------
#define APAD 40   // f16 row stride (32 data + 8 pad) = 80B, 16B-aligned

__global__ __launch_bounds__(256) void energy_mfma_kernel(
    const float* __restrict__ Qt, const float* __restrict__ Kt,
    float* __restrict__ ATT)
{
    const int b = blockIdx.z;
    const int n0 = blockIdx.y * 128;
    const int m0 = blockIdx.x * 128;
    const float* __restrict__ Qb = Qt + (size_t)b * NN * CC;
    const float* __restrict__ Kb = Kt + (size_t)b * NN * CC;
    float* __restrict__ Eb = ATT + (size_t)b * NN * NN;

    __shared__ f16 Asl[128 * APAD];
    __shared__ f16 Bsl[128 * APAD];

    const int tid = threadIdx.x;
    const int wave = tid >> 6, lane = tid & 63;
    const int wr = (wave >> 1) * 64, wc = (wave & 1) * 64;
    const int lrow = lane & 15, lk = (lane >> 4) * 8;

    f32x4 acc[4][4] = {};

    for (int k0 = 0; k0 < CC; k0 += 32) {
#pragma unroll
        for (int i = 0; i < 4; ++i) {
            int idx = tid + 256 * i;
            int r = idx >> 3, ch = idx & 7;
            float4 qa = *(const float4*)&Qb[(size_t)(n0 + r) * CC + k0 + ch * 4];
            float4 ka = *(const float4*)&Kb[(size_t)(m0 + r) * CC + k0 + ch * 4];
            f16x4 q16 = {(f16)qa.x, (f16)qa.y, (f16)qa.z, (f16)qa.w};
            f16x4 k16 = {(f16)ka.x, (f16)ka.y, (f16)ka.z, (f16)ka.w};
            *(f16x4*)&Asl[r * APAD + ch * 4] = q16;
            *(f16x4*)&Bsl[r * APAD + ch * 4] = k16;
        }
        __syncthreads();
        f16x8 af[4], bf[4];
#pragma unroll
        for (int i = 0; i < 4; ++i) {
            af[i] = *(const f16x8*)&Asl[(wr + i * 16 + lrow) * APAD + lk];
            bf[i] = *(const f16x8*)&Bsl[(wc + i * 16 + lrow) * APAD + lk];
        }
#pragma unroll
        for (int i = 0; i < 4; ++i)
#pragma unroll
            for (int j = 0; j < 4; ++j)
                acc[i][j] = __builtin_amdgcn_mfma_f32_16x16x32_f16(
                    af[i], bf[j], acc[i][j], 0, 0, 0);
        __syncthreads();
    }

#pragma unroll
    for (int i = 0; i < 4; ++i)
#pragma unroll
        for (int q = 0; q < 4; ++q) {
            int row = n0 + wr + i * 16 + (lane >> 4) * 4 + q;
#pragma unroll
            for (int j = 0; j < 4; ++j) {
                int col = m0 + wc + j * 16 + lrow;
                Eb[(size_t)row * NN + col] = acc[i][j][q];
            }
        }
}

// ---------------------------------------------------------------------------
// Kernel 3: in-place row softmax over last axis. One block per (b,n) row.
// ---------------------------------------------------------------------------
__global__ __launch_bounds__(256) void softmax_kernel(float* __restrict__ ATT)
{
    const size_t row = blockIdx.x;
    float* __restrict__ R = ATT + row * NN;
    const int tid = threadIdx.x;
    const int wave = tid >> 6, lane = tid & 63;

    float e[8];
#pragma unroll
    for (int j = 0; j < 8; ++j) e[j] = R[tid + 256 * j];

    float mx = e[0];
#pragma unroll
    for (int j = 1; j < 8; ++j) mx = fmaxf(mx, e[j]);
#pragma unroll
    for (int s = 1; s < 64; s <<= 1) mx = fmaxf(mx, __shfl_xor(mx, s));

    __shared__ float redm[4];
    if (lane == 0) redm[wave] = mx;
    __syncthreads();
    mx = fmaxf(fmaxf(redm[0], redm[1]), fmaxf(redm[2], redm[3]));

    float s = 0.f;
#pragma unroll
    for (int j = 0; j < 8; ++j) { e[j] = __expf(e[j] - mx); s += e[j]; }
#pragma unroll
    for (int t = 1; t < 64; t <<= 1) s += __shfl_xor(s, t);

    __shared__ float reds[4];
    if (lane == 0) reds[wave] = s;
    __syncthreads();
    s = reds[0] + reds[1] + reds[2] + reds[3];

    const float inv = 1.f / s;
#pragma unroll
    for (int j = 0; j < 8; ++j) R[tid + 256 * j] = e[j] * inv;
}

// ---------------------------------------------------------------------------
// Kernel 4: column sums
// ---------------------------------------------------------------------------
__global__ __launch_bounds__(256) void colsum_kernel(
    const float* __restrict__ ATT, float* __restrict__ colsum)
{
    const int b = blockIdx.z;
    const int m = blockIdx.x * 256 + threadIdx.x;
    const int n0 = blockIdx.y * 128;
    const float* __restrict__ Ab = ATT + (size_t)b * NN * NN;
    float s = 0.f;
    for (int n = n0; n < n0 + 128; ++n) s += Ab[(size_t)n * NN + m];
    atomicAdd(&colsum[b * NN + m], s);
}

// ---------------------------------------------------------------------------
// Kernel 5: x_r = V * (ATT*diag(rcv)); D = x - x_r  (MFMA f16)
// A = V[c][n] direct-staged; B = ATT[n][m] transpose-staged to [m][n].
// ---------------------------------------------------------------------------
#define BPAD 36   // f16 row stride = 72B (odd bank stride -> free 2-way)

__global__ __launch_bounds__(256) void xr_mfma_kernel(
    const float* __restrict__ V, const float* __restrict__ ATT,
    const float* __restrict__ colsum, const float* __restrict__ x,
    float* __restrict__ D)
{
    const int b  = blockIdx.z;
    const int c0 = blockIdx.y * 128;
    const int m0 = blockIdx.x * 128;
    const float* __restrict__ Vb = V   + (size_t)b * CC * NN;
    const float* __restrict__ Ab = ATT + (size_t)b * NN * NN;
    const float* __restrict__ Xb = x   + (size_t)b * CC * NN;
    float* __restrict__ Db       = D   + (size_t)b * CC * NN;

    __shared__ f16 Asl[128 * APAD];
    __shared__ f16 Bsl[128 * BPAD];
    __shared__ float rcv[128];

    const int tid = threadIdx.x;
    if (tid < 128) rcv[tid] = 1.f / (1e-9f + colsum[b * NN + m0 + tid]);
    __syncthreads();

    const int wave = tid >> 6, lane = tid & 63;
    const int wr = (wave >> 1) * 64, wc = (wave & 1) * 64;
    const int lrow = lane & 15, lk = (lane >> 4) * 8;

    f32x4 acc[4][4] = {};

    for (int k0 = 0; k0 < NN; k0 += 32) {
        // A: V rows c, k=n contiguous — direct copy
#pragma unroll
        for (int i = 0; i < 4; ++i) {
            int idx = tid + 256 * i;
            int r = idx >> 3, ch = idx & 7;
            float4 va = *(const float4*)&Vb[(size_t)(c0 + r) * NN + k0 + ch * 4];
            f16x4 v16 = {(f16)va.x, (f16)va.y, (f16)va.z, (f16)va.w};
            *(f16x4*)&Asl[r * APAD + ch * 4] = v16;
        }
        // B: transpose-stage 32 n x 128 m -> Bsl[m][n], fold rcv[m]
#pragma unroll
        for (int i = 0; i < 8; ++i) {
            int idx = tid + 256 * i;          // 0..2047
            int m = idx & 127, np = idx >> 7; // np 0..15
            int n = k0 + np * 2;
            float s = rcv[m];
            float a0 = Ab[(size_t)n * NN + m0 + m] * s;
            float a1 = Ab[(size_t)(n + 1) * NN + m0 + m] * s;
            f16x2 p = {(f16)a0, (f16)a1};
            *(f16x2*)&Bsl[m * BPAD + np * 2] = p;
        }
        __syncthreads();
        f16x8 af[4], bf[4];
#pragma unroll
        for (int i = 0; i < 4; ++i) {
            af[i] = *(const f16x8*)&Asl[(wr + i * 16 + lrow) * APAD + lk];
            f16x4 lo = *(const f16x4*)&Bsl[(wc + i * 16 + lrow) * BPAD + lk];
            f16x4 hi = *(const f16x4*)&Bsl[(wc + i * 16 + lrow) * BPAD + lk + 4];
            f16x8 bb;
            bb[0] = lo[0]; bb[1] = lo[1]; bb[2] = lo[2]; bb[3] = lo[3];
            bb[4] = hi[0]; bb[5] = hi[1]; bb[6] = hi[2]; bb[7] = hi[3];
            bf[i] = bb;
        }
#pragma unroll
        for (int i = 0; i < 4; ++i)
#pragma unroll
            for (int j = 0; j < 4; ++j)
                acc[i][j] = __builtin_amdgcn_mfma_f32_16x16x32_f16(
                    af[i], bf[j], acc[i][j], 0, 0, 0);
        __syncthreads();
    }

#pragma unroll
    for (int i = 0; i < 4; ++i)
#pragma unroll
        for (int q = 0; q < 4; ++q) {
            int row = c0 + wr + i * 16 + (lane >> 4) * 4 + q;
#pragma unroll
            for (int j = 0; j < 4; ++j) {
                int col = m0 + wc + j * 16 + lrow;
                size_t off = (size_t)row * NN + col;
                Db[off] = Xb[off] - acc[i][j][q];
            }
        }
}

// ---------------------------------------------------------------------------
// Kernel 6: XZ = alpha*(Wt*D + bt) + beta; accumulate BN sums per channel.
// ---------------------------------------------------------------------------
__global__ __launch_bounds__(256) void xz_kernel(
    const float* __restrict__ Wt, const float* __restrict__ D,
    const float* __restrict__ bt, const float* __restrict__ alpha,
    const float* __restrict__ beta, float* __restrict__ XZ,
    float* __restrict__ bnsum, float* __restrict__ bnsumsq)
{
    const int b = blockIdx.z;
    const int m0 = blockIdx.y * 64;
    const int n0 = blockIdx.x * 64;
    const float* __restrict__ Db = D  + (size_t)b * CC * NN;
    float* __restrict__ Zb       = XZ + (size_t)b * CC * NN;

    const int tid = threadIdx.x;
    const int tm = tid >> 4, tn = tid & 15;

    __shared__ float As[16][68];
    __shared__ float Bs[16][64];

    float acc[4][4] = {};

    for (int k0 = 0; k0 < CC; k0 += 16) {
#pragma unroll
        for (int i = 0; i < 4; ++i) {
            int idx = tid + 256 * i;
            int m = idx >> 4, k = idx & 15;
            As[k][m] = Wt[(size_t)(m0 + m) * CC + k0 + k];
        }
#pragma unroll
        for (int i = 0; i < 4; ++i) {
            int idx = tid + 256 * i;
            int k = idx >> 6, n = idx & 63;
            Bs[k][n] = Db[(size_t)(k0 + k) * NN + n0 + n];
        }
        __syncthreads();
#pragma unroll
        for (int k = 0; k < 16; ++k) {
            float4 a4 = *(const float4*)&As[k][tm * 4];
            float4 b4 = *(const float4*)&Bs[k][tn * 4];
            float av[4] = {a4.x, a4.y, a4.z, a4.w};
            float bw[4] = {b4.x, b4.y, b4.z, b4.w};
#pragma unroll
            for (int i = 0; i < 4; ++i)
#pragma unroll
                for (int j = 0; j < 4; ++j) acc[i][j] += av[i] * bw[j];
        }
        __syncthreads();
    }

#pragma unroll
    for (int i = 0; i < 4; ++i) {
        int row = m0 + tm * 4 + i;
        const float al = alpha[row], be = beta[row], bb = bt[row];
        float4 z;
        z.x = al * (acc[i][0] + bb) + be;
        z.y = al * (acc[i][1] + bb) + be;
        z.z = al * (acc[i][2] + bb) + be;
        z.w = al * (acc[i][3] + bb) + be;
        *(float4*)&Zb[(size_t)row * NN + n0 + tn * 4] = z;

        float ps  = z.x + z.y + z.z + z.w;
        float ps2 = z.x * z.x + z.y * z.y + z.z * z.z + z.w * z.w;
#pragma unroll
        for (int s = 1; s < 16; s <<= 1) {
            ps  += __shfl_xor(ps, s);
            ps2 += __shfl_xor(ps2, s);
        }
        if (tn == 0) {
            atomicAdd(&bnsum[row], ps);
            atomicAdd(&bnsumsq[row], ps2);
        }
    }
}

// ---------------------------------------------------------------------------
// Kernel 7: out = x + relu(gamma*(XZ-mean)*rsqrt(var+eps)+beta)
// ---------------------------------------------------------------------------
__global__ __launch_bounds__(256) void final_kernel(
    const float* __restrict__ x, const float* __restrict__ XZ,
    const float* __restrict__ bnsum, const float* __restrict__ bnsumsq,
    const float* __restrict__ gamma, const float* __restrict__ bbeta,
    float* __restrict__ out)
{
    const int i4 = blockIdx.x * 256 + threadIdx.x;
    const int elem = i4 * 4;
    const int c = (elem / NN) % CC;
    const float inv_cnt = 1.f / (float)(BB * NN);
    const float mean = bnsum[c] * inv_cnt;
    const float var  = bnsumsq[c] * inv_cnt - mean * mean;
    const float rs = rsqrtf(var + BN_EPS);
    const float g = gamma[c], bb = bbeta[c];

    float4 z = *(const float4*)&XZ[elem];
    float4 xv = *(const float4*)&x[elem];
    float4 o;
    o.x = xv.x + fmaxf(g * (z.x - mean) * rs + bb, 0.f);
    o.y = xv.y + fmaxf(g * (z.y - mean) * rs + bb, 0.f);
    o.z = xv.z + fmaxf(g * (z.z - mean) * rs + bb, 0.f);
    o.w = xv.w + fmaxf(g * (z.w - mean) * rs + bb, 0.f);
    *(float4*)&out[elem] = o;
}

// ---------------------------------------------------------------------------

extern "C" void kernel_launch(void* const* d_in, const int* in_sizes, int n_in,
                              void* d_out, int out_size, void* d_ws, size_t ws_size,
                              hipStream_t stream) {
    const float* x     = (const float*)d_in[0];
    const float* Wq    = (const float*)d_in[1];
    const float* Wk    = (const float*)d_in[2];
    const float* Wv    = (const float*)d_in[3];
    const float* bv    = (const float*)d_in[4];
    const float* Wt    = (const float*)d_in[5];
    const float* bt    = (const float*)d_in[6];
    const float* gamma = (const float*)d_in[7];
    const float* bbeta = (const float*)d_in[8];
    const float* alpha = (const float*)d_in[9];
    const float* beta  = (const float*)d_in[10];
    float* out = (float*)d_out;

    float* ws = (float*)d_ws;
    const size_t BCN = (size_t)BB * CC * NN;
    float* Qt     = ws;                              // [B][N][C]
    float* Kt     = ws + BCN;                        // [B][N][C]
    float* V      = ws + 2 * BCN;                    // [B][C][N]
    float* ATT    = ws + 3 * BCN;                    // [B][N][N]
    float* XZ     = ATT + (size_t)BB * NN * NN;
    float* colsum = XZ + BCN;
    float* bnsum  = colsum + (size_t)BB * NN;
    float* bnsumsq = bnsum + CC;
    float* D      = Qt;                              // reuse Qt after energy

    hipMemsetAsync(colsum, 0, (size_t)(BB * NN + 2 * CC) * sizeof(float), stream);

    proj_kernel<<<dim3(NN / 64, CC / 64, 3 * BB), 256, 0, stream>>>(
        x, Wq, Wk, Wv, bv, Qt, Kt, V);
    energy_mfma_kernel<<<dim3(NN / 128, NN / 128, BB), 256, 0, stream>>>(
        Qt, Kt, ATT);
    softmax_kernel<<<dim3(BB * NN), 256, 0, stream>>>(ATT);
    colsum_kernel<<<dim3(NN / 256, 16, BB), 256, 0, stream>>>(ATT, colsum);
    xr_mfma_kernel<<<dim3(NN / 128, CC / 128, BB), 256, 0, stream>>>(
        V, ATT, colsum, x, D);
    xz_kernel<<<dim3(NN / 64, CC / 64, BB), 256, 0, stream>>>(
        Wt, D, bt, alpha, beta, XZ, bnsum, bnsumsq);
    final_kernel<<<dim3((int)(BCN / 4 / 256)), 256, 0, stream>>>(
        x, XZ, bnsum, bnsumsq, gamma, bbeta, out);
}

// Round 6
// 300.541 us; speedup vs baseline: 2.3665x; 1.1360x over previous
//
#include <hip/hip_runtime.h>
#include <math.h>

#define BB 8
#define CC 256
#define NN 2048
static constexpr float BN_EPS = 1e-5f;

typedef _Float16 f16;
typedef f16 f16x2 __attribute__((ext_vector_type(2)));
typedef f16 f16x4 __attribute__((ext_vector_type(4)));
typedef f16 f16x8 __attribute__((ext_vector_type(8)));
typedef float f32x4 __attribute__((ext_vector_type(4)));

#define APAD 40   // f16 row stride (32 data + 8 pad) = 80B, 16B-aligned
#define BPAD 36   // f16 row stride = 72B

// ---------------------------------------------------------------------------
// Prep A: four C x C weight matrices -> hi/lo f16 planes (concatenated).
// ---------------------------------------------------------------------------
__global__ __launch_bounds__(256) void prep_w_kernel(
    const float* __restrict__ Wq, const float* __restrict__ Wk,
    const float* __restrict__ Wv, const float* __restrict__ Wt,
    f16* __restrict__ Whi, f16* __restrict__ Wlo)
{
    int idx = (blockIdx.x * 256 + threadIdx.x) * 8;   // over 4*C*C
    const float* s = (idx < 65536) ? Wq : (idx < 131072) ? Wk
                    : (idx < 196608) ? Wv : Wt;
    int off = idx & 65535;
    float4 a = *(const float4*)&s[off];
    float4 b = *(const float4*)&s[off + 4];
    float v[8] = {a.x, a.y, a.z, a.w, b.x, b.y, b.z, b.w};
    f16x8 h, l;
#pragma unroll
    for (int j = 0; j < 8; ++j) {
        f16 hh = (f16)v[j];
        f16 ll = (f16)(v[j] - (float)hh);
        h[j] = hh;
        l[j] = ll;
    }
    *(f16x8*)&Whi[idx] = h;
    *(f16x8*)&Wlo[idx] = l;
}

// ---------------------------------------------------------------------------
// Prep B: Xhi/Xlo[b][n][c] = split (f16) of x[b][c][n]  (LDS-tiled transpose)
// ---------------------------------------------------------------------------
__global__ __launch_bounds__(256) void prep_x_kernel(
    const float* __restrict__ x, f16* __restrict__ Xhi, f16* __restrict__ Xlo)
{
    const int b = blockIdx.z, c0 = blockIdx.y * 64, n0 = blockIdx.x * 64;
    const float* __restrict__ Xb = x + (size_t)b * CC * NN;
    f16* __restrict__ Oh = Xhi + (size_t)b * NN * CC;
    f16* __restrict__ Ol = Xlo + (size_t)b * NN * CC;
    __shared__ f16 Th[64][72];
    __shared__ f16 Tl[64][72];
    const int tid = threadIdx.x;
    const int r = tid >> 4, c4 = (tid & 15) * 4;
#pragma unroll
    for (int i = 0; i < 4; ++i) {
        int rr = r + i * 16;
        float4 v = *(const float4*)&Xb[(size_t)(c0 + rr) * NN + n0 + c4];
        float vv[4] = {v.x, v.y, v.z, v.w};
#pragma unroll
        for (int j = 0; j < 4; ++j) {
            f16 hh = (f16)vv[j];
            f16 ll = (f16)(vv[j] - (float)hh);
            Th[c4 + j][rr] = hh;
            Tl[c4 + j][rr] = ll;
        }
    }
    __syncthreads();
#pragma unroll
    for (int i = 0; i < 2; ++i) {
        int idx = tid + 256 * i;
        int n = idx >> 3, cg = (idx & 7) * 8;
        *(f16x8*)&Oh[(size_t)(n0 + n) * CC + c0 + cg] = *(f16x8*)&Th[n][cg];
        *(f16x8*)&Ol[(size_t)(n0 + n) * CC + c0 + cg] = *(f16x8*)&Tl[n][cg];
    }
}

// ---------------------------------------------------------------------------
// Kernel 1: projections via split-precision MFMA (hi*hi + hi*lo + lo*hi).
// which 0/1 -> Qf/Kf fp32 [b][n][c]; which 2 -> V16 f16 [b][c][n] (+bv).
// ---------------------------------------------------------------------------
__global__ __launch_bounds__(256) void proj_mfma_kernel(
    const f16* __restrict__ Whi, const f16* __restrict__ Wlo,
    const f16* __restrict__ Xhi, const f16* __restrict__ Xlo,
    const float* __restrict__ bv,
    float* __restrict__ Qf, float* __restrict__ Kf, f16* __restrict__ V16)
{
    const int which = blockIdx.z >> 3;
    const int b     = blockIdx.z & 7;
    const f16* __restrict__ Wh = Whi + (size_t)which * CC * CC;
    const f16* __restrict__ Wl = Wlo + (size_t)which * CC * CC;
    const f16* __restrict__ Xh = Xhi + (size_t)b * NN * CC;
    const f16* __restrict__ Xl = Xlo + (size_t)b * NN * CC;

    const int m0 = blockIdx.y * 128;   // output channels
    const int n0 = blockIdx.x * 128;   // points

    __shared__ f16 Ah[128 * APAD];
    __shared__ f16 Al[128 * APAD];
    __shared__ f16 Bh[128 * APAD];
    __shared__ f16 Bl[128 * APAD];

    const int tid = threadIdx.x;
    const int wave = tid >> 6, lane = tid & 63;
    const int wr = (wave >> 1) * 64, wc = (wave & 1) * 64;
    const int lrow = lane & 15, lk = (lane >> 4) * 8;

    f32x4 acc[4][4] = {};

    for (int k0 = 0; k0 < CC; k0 += 32) {
#pragma unroll
        for (int i = 0; i < 2; ++i) {
            int idx = tid + 256 * i;
            int r = idx >> 2, ch = idx & 3;
            *(f16x8*)&Ah[r * APAD + ch * 8] =
                *(const f16x8*)&Wh[(size_t)(m0 + r) * CC + k0 + ch * 8];
            *(f16x8*)&Al[r * APAD + ch * 8] =
                *(const f16x8*)&Wl[(size_t)(m0 + r) * CC + k0 + ch * 8];
            *(f16x8*)&Bh[r * APAD + ch * 8] =
                *(const f16x8*)&Xh[(size_t)(n0 + r) * CC + k0 + ch * 8];
            *(f16x8*)&Bl[r * APAD + ch * 8] =
                *(const f16x8*)&Xl[(size_t)(n0 + r) * CC + k0 + ch * 8];
        }
        __syncthreads();
        f16x8 ah[4], al[4], bh[4], bl[4];
#pragma unroll
        for (int i = 0; i < 4; ++i) {
            ah[i] = *(const f16x8*)&Ah[(wr + i * 16 + lrow) * APAD + lk];
            al[i] = *(const f16x8*)&Al[(wr + i * 16 + lrow) * APAD + lk];
            bh[i] = *(const f16x8*)&Bh[(wc + i * 16 + lrow) * APAD + lk];
            bl[i] = *(const f16x8*)&Bl[(wc + i * 16 + lrow) * APAD + lk];
        }
#pragma unroll
        for (int i = 0; i < 4; ++i)
#pragma unroll
            for (int j = 0; j < 4; ++j) {
                acc[i][j] = __builtin_amdgcn_mfma_f32_16x16x32_f16(
                    ah[i], bh[j], acc[i][j], 0, 0, 0);
                acc[i][j] = __builtin_amdgcn_mfma_f32_16x16x32_f16(
                    ah[i], bl[j], acc[i][j], 0, 0, 0);
                acc[i][j] = __builtin_amdgcn_mfma_f32_16x16x32_f16(
                    al[i], bh[j], acc[i][j], 0, 0, 0);
            }
        __syncthreads();
    }

    if (which < 2) {
        float* __restrict__ Ot = ((which == 0) ? Qf : Kf) + (size_t)b * NN * CC;
#pragma unroll
        for (int i = 0; i < 4; ++i) {
            int cb = m0 + wr + i * 16 + (lane >> 4) * 4;
#pragma unroll
            for (int j = 0; j < 4; ++j) {
                int n = n0 + wc + j * 16 + lrow;
                *(f32x4*)&Ot[(size_t)n * CC + cb] = acc[i][j];
            }
        }
    } else {
        f16* __restrict__ Vb = V16 + (size_t)b * CC * NN;
#pragma unroll
        for (int i = 0; i < 4; ++i) {
            int cb = m0 + wr + i * 16 + (lane >> 4) * 4;
#pragma unroll
            for (int q = 0; q < 4; ++q) {
                float bvv = bv[cb + q];
#pragma unroll
                for (int j = 0; j < 4; ++j) {
                    int n = n0 + wc + j * 16 + lrow;
                    Vb[(size_t)(cb + q) * NN + n] = (f16)(acc[i][j][q] + bvv);
                }
            }
        }
    }
}

// ---------------------------------------------------------------------------
// Kernel 2: energy = Qf . Kf^T via split-precision MFMA -> fp32 logits.
// ---------------------------------------------------------------------------
__global__ __launch_bounds__(256) void energy_mfma_kernel(
    const float* __restrict__ Qf, const float* __restrict__ Kf,
    float* __restrict__ ATT)
{
    const int b = blockIdx.z;
    const int n0 = blockIdx.y * 128;
    const int m0 = blockIdx.x * 128;
    const float* __restrict__ Qb = Qf + (size_t)b * NN * CC;
    const float* __restrict__ Kb = Kf + (size_t)b * NN * CC;
    float* __restrict__ Eb = ATT + (size_t)b * NN * NN;

    __shared__ f16 Ah[128 * APAD];
    __shared__ f16 Al[128 * APAD];
    __shared__ f16 Bh[128 * APAD];
    __shared__ f16 Bl[128 * APAD];

    const int tid = threadIdx.x;
    const int wave = tid >> 6, lane = tid & 63;
    const int wr = (wave >> 1) * 64, wc = (wave & 1) * 64;
    const int lrow = lane & 15, lk = (lane >> 4) * 8;

    f32x4 acc[4][4] = {};

    for (int k0 = 0; k0 < CC; k0 += 32) {
#pragma unroll
        for (int i = 0; i < 4; ++i) {
            int idx = tid + 256 * i;          // 0..1023
            int r = idx >> 3, c4 = (idx & 7) * 4;
            float4 q = *(const float4*)&Qb[(size_t)(n0 + r) * CC + k0 + c4];
            float4 k = *(const float4*)&Kb[(size_t)(m0 + r) * CC + k0 + c4];
            float qv[4] = {q.x, q.y, q.z, q.w};
            float kv[4] = {k.x, k.y, k.z, k.w};
            f16x4 qh, ql, kh, kl;
#pragma unroll
            for (int j = 0; j < 4; ++j) {
                f16 h1 = (f16)qv[j];
                f16 l1 = (f16)(qv[j] - (float)h1);
                qh[j] = h1; ql[j] = l1;
                f16 h2 = (f16)kv[j];
                f16 l2 = (f16)(kv[j] - (float)h2);
                kh[j] = h2; kl[j] = l2;
            }
            *(f16x4*)&Ah[r * APAD + c4] = qh;
            *(f16x4*)&Al[r * APAD + c4] = ql;
            *(f16x4*)&Bh[r * APAD + c4] = kh;
            *(f16x4*)&Bl[r * APAD + c4] = kl;
        }
        __syncthreads();
        f16x8 ah[4], al[4], bh[4], bl[4];
#pragma unroll
        for (int i = 0; i < 4; ++i) {
            ah[i] = *(const f16x8*)&Ah[(wr + i * 16 + lrow) * APAD + lk];
            al[i] = *(const f16x8*)&Al[(wr + i * 16 + lrow) * APAD + lk];
            bh[i] = *(const f16x8*)&Bh[(wc + i * 16 + lrow) * APAD + lk];
            bl[i] = *(const f16x8*)&Bl[(wc + i * 16 + lrow) * APAD + lk];
        }
#pragma unroll
        for (int i = 0; i < 4; ++i)
#pragma unroll
            for (int j = 0; j < 4; ++j) {
                acc[i][j] = __builtin_amdgcn_mfma_f32_16x16x32_f16(
                    ah[i], bh[j], acc[i][j], 0, 0, 0);
                acc[i][j] = __builtin_amdgcn_mfma_f32_16x16x32_f16(
                    ah[i], bl[j], acc[i][j], 0, 0, 0);
                acc[i][j] = __builtin_amdgcn_mfma_f32_16x16x32_f16(
                    al[i], bh[j], acc[i][j], 0, 0, 0);
            }
        __syncthreads();
    }

#pragma unroll
    for (int i = 0; i < 4; ++i)
#pragma unroll
        for (int q = 0; q < 4; ++q) {
            int row = n0 + wr + i * 16 + (lane >> 4) * 4 + q;
#pragma unroll
            for (int j = 0; j < 4; ++j) {
                int col = m0 + wc + j * 16 + lrow;
                Eb[(size_t)row * NN + col] = acc[i][j][q];
            }
        }
}

// ---------------------------------------------------------------------------
// Kernel 3: in-place fp32 row softmax (fp32 out — double-norm needs the
// full dynamic range; f16 storage flushes tiny columns -> O(1) errors).
// ---------------------------------------------------------------------------
__global__ __launch_bounds__(256) void softmax_kernel(float* __restrict__ ATT)
{
    const size_t row = blockIdx.x;
    float* __restrict__ R = ATT + row * NN;
    const int tid = threadIdx.x;
    const int wave = tid >> 6, lane = tid & 63;

    float e[8];
#pragma unroll
    for (int j = 0; j < 8; ++j) e[j] = R[tid + 256 * j];

    float mx = e[0];
#pragma unroll
    for (int j = 1; j < 8; ++j) mx = fmaxf(mx, e[j]);
#pragma unroll
    for (int s = 1; s < 64; s <<= 1) mx = fmaxf(mx, __shfl_xor(mx, s));

    __shared__ float redm[4];
    if (lane == 0) redm[wave] = mx;
    __syncthreads();
    mx = fmaxf(fmaxf(redm[0], redm[1]), fmaxf(redm[2], redm[3]));

    float s = 0.f;
#pragma unroll
    for (int j = 0; j < 8; ++j) { e[j] = __expf(e[j] - mx); s += e[j]; }
#pragma unroll
    for (int t = 1; t < 64; t <<= 1) s += __shfl_xor(s, t);

    __shared__ float reds[4];
    if (lane == 0) reds[wave] = s;
    __syncthreads();
    s = reds[0] + reds[1] + reds[2] + reds[3];

    const float inv = 1.f / s;
#pragma unroll
    for (int j = 0; j < 8; ++j) R[tid + 256 * j] = e[j] * inv;
}

// ---------------------------------------------------------------------------
// Kernel 4: column sums (fp32)
// ---------------------------------------------------------------------------
__global__ __launch_bounds__(256) void colsum_kernel(
    const float* __restrict__ ATT, float* __restrict__ colsum)
{
    const int b = blockIdx.z;
    const int m = blockIdx.x * 256 + threadIdx.x;
    const int n0 = blockIdx.y * 128;
    const float* __restrict__ Ab = ATT + (size_t)b * NN * NN;
    float s = 0.f;
    for (int n = n0; n < n0 + 128; ++n) s += Ab[(size_t)n * NN + m];
    atomicAdd(&colsum[b * NN + m], s);
}

// ---------------------------------------------------------------------------
// Kernel 5: x_r = V16 * (ATT*diag(rcv)); Dt16[n][c] = (f16)(x - x_r)
// B staged from fp32 ATT; f16 conversion AFTER the rcv scale (range-safe).
// ---------------------------------------------------------------------------
__global__ __launch_bounds__(256) void xr_mfma_kernel(
    const f16* __restrict__ V16, const float* __restrict__ ATT,
    const float* __restrict__ colsum, const float* __restrict__ x,
    f16* __restrict__ Dt16)
{
    const int b  = blockIdx.z;
    const int c0 = blockIdx.y * 128;
    const int m0 = blockIdx.x * 128;
    const f16* __restrict__ Vb = V16 + (size_t)b * CC * NN;
    const float* __restrict__ Ab = ATT + (size_t)b * NN * NN;
    const float* __restrict__ Xb = x + (size_t)b * CC * NN;
    f16* __restrict__ Db = Dt16 + (size_t)b * NN * CC;

    __shared__ f16 Asl[128 * APAD];
    __shared__ f16 Bsl[128 * BPAD];
    __shared__ float rcv[128];

    const int tid = threadIdx.x;
    if (tid < 128) rcv[tid] = 1.f / (1e-9f + colsum[b * NN + m0 + tid]);
    __syncthreads();

    const int wave = tid >> 6, lane = tid & 63;
    const int wr = (wave >> 1) * 64, wc = (wave & 1) * 64;
    const int lrow = lane & 15, lk = (lane >> 4) * 8;

    f32x4 acc[4][4] = {};

    for (int k0 = 0; k0 < NN; k0 += 32) {
#pragma unroll
        for (int i = 0; i < 2; ++i) {
            int idx = tid + 256 * i;
            int r = idx >> 2, ch = idx & 3;
            *(f16x8*)&Asl[r * APAD + ch * 8] =
                *(const f16x8*)&Vb[(size_t)(c0 + r) * NN + k0 + ch * 8];
        }
#pragma unroll
        for (int i = 0; i < 8; ++i) {
            int idx = tid + 256 * i;
            int m = idx & 127, np = idx >> 7;
            int n = k0 + np * 2;
            float sc = rcv[m];
            float a0 = Ab[(size_t)n * NN + m0 + m] * sc;
            float a1 = Ab[(size_t)(n + 1) * NN + m0 + m] * sc;
            f16x2 p = {(f16)a0, (f16)a1};
            *(f16x2*)&Bsl[m * BPAD + np * 2] = p;
        }
        __syncthreads();
        f16x8 af[4], bf[4];
#pragma unroll
        for (int i = 0; i < 4; ++i) {
            af[i] = *(const f16x8*)&Asl[(wr + i * 16 + lrow) * APAD + lk];
            f16x4 lo = *(const f16x4*)&Bsl[(wc + i * 16 + lrow) * BPAD + lk];
            f16x4 hi = *(const f16x4*)&Bsl[(wc + i * 16 + lrow) * BPAD + lk + 4];
            f16x8 bb;
            bb[0] = lo[0]; bb[1] = lo[1]; bb[2] = lo[2]; bb[3] = lo[3];
            bb[4] = hi[0]; bb[5] = hi[1]; bb[6] = hi[2]; bb[7] = hi[3];
            bf[i] = bb;
        }
#pragma unroll
        for (int i = 0; i < 4; ++i)
#pragma unroll
            for (int j = 0; j < 4; ++j)
                acc[i][j] = __builtin_amdgcn_mfma_f32_16x16x32_f16(
                    af[i], bf[j], acc[i][j], 0, 0, 0);
        __syncthreads();
    }

#pragma unroll
    for (int i = 0; i < 4; ++i) {
        int cb = c0 + wr + i * 16 + (lane >> 4) * 4;
#pragma unroll
        for (int j = 0; j < 4; ++j) {
            int n = m0 + wc + j * 16 + lrow;
            f16x4 dv;
#pragma unroll
            for (int q = 0; q < 4; ++q)
                dv[q] = (f16)(Xb[(size_t)(cb + q) * NN + n] - acc[i][j][q]);
            *(f16x4*)&Db[(size_t)n * CC + cb] = dv;
        }
    }
}

// ---------------------------------------------------------------------------
// Kernel 6: XZ = alpha*(Wt*Dt16 + bt) + beta (fp32) + BN partial sums
// ---------------------------------------------------------------------------
__global__ __launch_bounds__(256) void xz_mfma_kernel(
    const f16* __restrict__ Whi, const f16* __restrict__ Dt16,
    const float* __restrict__ bt, const float* __restrict__ alpha,
    const float* __restrict__ beta, float* __restrict__ XZ,
    float* __restrict__ bnsum, float* __restrict__ bnsumsq)
{
    const int b = blockIdx.z;
    const int m0 = blockIdx.y * 128;
    const int n0 = blockIdx.x * 128;
    const f16* __restrict__ Wb = Whi + (size_t)3 * CC * CC;   // Wt (hi)
    const f16* __restrict__ Db = Dt16 + (size_t)b * NN * CC;
    float* __restrict__ Zb = XZ + (size_t)b * CC * NN;

    __shared__ f16 Asl[128 * APAD];
    __shared__ f16 Bsl[128 * APAD];

    const int tid = threadIdx.x;
    const int wave = tid >> 6, lane = tid & 63;
    const int wr = (wave >> 1) * 64, wc = (wave & 1) * 64;
    const int lrow = lane & 15, lk = (lane >> 4) * 8;

    f32x4 acc[4][4] = {};

    for (int k0 = 0; k0 < CC; k0 += 32) {
#pragma unroll
        for (int i = 0; i < 2; ++i) {
            int idx = tid + 256 * i;
            int r = idx >> 2, ch = idx & 3;
            *(f16x8*)&Asl[r * APAD + ch * 8] =
                *(const f16x8*)&Wb[(size_t)(m0 + r) * CC + k0 + ch * 8];
            *(f16x8*)&Bsl[r * APAD + ch * 8] =
                *(const f16x8*)&Db[(size_t)(n0 + r) * CC + k0 + ch * 8];
        }
        __syncthreads();
        f16x8 af[4], bf[4];
#pragma unroll
        for (int i = 0; i < 4; ++i) {
            af[i] = *(const f16x8*)&Asl[(wr + i * 16 + lrow) * APAD + lk];
            bf[i] = *(const f16x8*)&Bsl[(wc + i * 16 + lrow) * APAD + lk];
        }
#pragma unroll
        for (int i = 0; i < 4; ++i)
#pragma unroll
            for (int j = 0; j < 4; ++j)
                acc[i][j] = __builtin_amdgcn_mfma_f32_16x16x32_f16(
                    af[i], bf[j], acc[i][j], 0, 0, 0);
        __syncthreads();
    }

#pragma unroll
    for (int i = 0; i < 4; ++i) {
#pragma unroll
        for (int q = 0; q < 4; ++q) {
            int o = m0 + wr + i * 16 + (lane >> 4) * 4 + q;
            float al = alpha[o], be = beta[o], bb = bt[o];
            float s1 = 0.f, s2 = 0.f;
#pragma unroll
            for (int j = 0; j < 4; ++j) {
                int n = n0 + wc + j * 16 + lrow;
                float z = al * (acc[i][j][q] + bb) + be;
                Zb[(size_t)o * NN + n] = z;
                s1 += z; s2 += z * z;
            }
#pragma unroll
            for (int d = 1; d < 16; d <<= 1) {
                s1 += __shfl_xor(s1, d);
                s2 += __shfl_xor(s2, d);
            }
            if (lrow == 0) {
                atomicAdd(&bnsum[o], s1);
                atomicAdd(&bnsumsq[o], s2);
            }
        }
    }
}

// ---------------------------------------------------------------------------
// Kernel 7: out = x + relu(gamma*(XZ-mean)*rsqrt(var+eps)+beta)
// ---------------------------------------------------------------------------
__global__ __launch_bounds__(256) void final_kernel(
    const float* __restrict__ x, const float* __restrict__ XZ,
    const float* __restrict__ bnsum, const float* __restrict__ bnsumsq,
    const float* __restrict__ gamma, const float* __restrict__ bbeta,
    float* __restrict__ out)
{
    const int i4 = blockIdx.x * 256 + threadIdx.x;
    const int elem = i4 * 4;
    const int c = (elem / NN) % CC;
    const float inv_cnt = 1.f / (float)(BB * NN);
    const float mean = bnsum[c] * inv_cnt;
    const float var  = bnsumsq[c] * inv_cnt - mean * mean;
    const float rs = rsqrtf(var + BN_EPS);
    const float g = gamma[c], bb = bbeta[c];

    float4 z = *(const float4*)&XZ[elem];
    float4 xv = *(const float4*)&x[elem];
    float4 o;
    o.x = xv.x + fmaxf(g * (z.x - mean) * rs + bb, 0.f);
    o.y = xv.y + fmaxf(g * (z.y - mean) * rs + bb, 0.f);
    o.z = xv.z + fmaxf(g * (z.z - mean) * rs + bb, 0.f);
    o.w = xv.w + fmaxf(g * (z.w - mean) * rs + bb, 0.f);
    *(float4*)&out[elem] = o;
}

// ---------------------------------------------------------------------------

extern "C" void kernel_launch(void* const* d_in, const int* in_sizes, int n_in,
                              void* d_out, int out_size, void* d_ws, size_t ws_size,
                              hipStream_t stream) {
    const float* x     = (const float*)d_in[0];
    const float* Wq    = (const float*)d_in[1];
    const float* Wk    = (const float*)d_in[2];
    const float* Wv    = (const float*)d_in[3];
    const float* bv    = (const float*)d_in[4];
    const float* Wt    = (const float*)d_in[5];
    const float* bt    = (const float*)d_in[6];
    const float* gamma = (const float*)d_in[7];
    const float* bbeta = (const float*)d_in[8];
    const float* alpha = (const float*)d_in[9];
    const float* beta  = (const float*)d_in[10];
    float* out = (float*)d_out;

    const size_t BCN = (size_t)BB * CC * NN;   // 4,194,304 elements
    const size_t WSZ = (size_t)4 * CC * CC;    // 262,144

    f16* Whi = (f16*)d_ws;                     // 4 x [C][C] hi
    f16* Wlo = Whi + WSZ;                      // 4 x [C][C] lo
    f16* V16 = Wlo + WSZ;                      // [B][C][N]
    float* Qf = (float*)(V16 + BCN);           // [B][N][C] fp32
    float* Kf = Qf + BCN;                      // [B][N][C] fp32
    float* ATT = Kf + BCN;                     // [B][N][N] fp32
    float* XZ  = ATT + (size_t)BB * NN * NN;   // [B][C][N] fp32
    float* colsum  = XZ + BCN;                 // [B][N]
    float* bnsum   = colsum + (size_t)BB * NN; // [C]
    float* bnsumsq = bnsum + CC;               // [C]

    // Xhi/Xlo overlay batch-0's ATT slab (dead by the time energy writes it).
    f16* Xhi = (f16*)ATT;                      // [B][N][C]
    f16* Xlo = Xhi + BCN;                      // [B][N][C]
    f16* Dt16 = (f16*)Qf;                      // reuse Qf after energy

    hipMemsetAsync(colsum, 0, (size_t)(BB * NN + 2 * CC) * sizeof(float), stream);

    prep_w_kernel<<<dim3(4 * CC * CC / 2048), 256, 0, stream>>>(
        Wq, Wk, Wv, Wt, Whi, Wlo);
    prep_x_kernel<<<dim3(NN / 64, CC / 64, BB), 256, 0, stream>>>(x, Xhi, Xlo);
    proj_mfma_kernel<<<dim3(NN / 128, CC / 128, 3 * BB), 256, 0, stream>>>(
        Whi, Wlo, Xhi, Xlo, bv, Qf, Kf, V16);
    energy_mfma_kernel<<<dim3(NN / 128, NN / 128, BB), 256, 0, stream>>>(
        Qf, Kf, ATT);
    softmax_kernel<<<dim3(BB * NN), 256, 0, stream>>>(ATT);
    colsum_kernel<<<dim3(NN / 256, 16, BB), 256, 0, stream>>>(ATT, colsum);
    xr_mfma_kernel<<<dim3(NN / 128, CC / 128, BB), 256, 0, stream>>>(
        V16, ATT, colsum, x, Dt16);
    xz_mfma_kernel<<<dim3(NN / 128, CC / 128, BB), 256, 0, stream>>>(
        Whi, Dt16, bt, alpha, beta, XZ, bnsum, bnsumsq);
    final_kernel<<<dim3((int)(BCN / 4 / 256)), 256, 0, stream>>>(
        x, XZ, bnsum, bnsumsq, gamma, bbeta, out);
}

// Round 7
// 277.253 us; speedup vs baseline: 2.5652x; 1.0840x over previous
//
#include <hip/hip_runtime.h>
#include <hip/hip_bf16.h>
#include <math.h>

#define BB 8
#define CC 256
#define NN 2048
static constexpr float BN_EPS = 1e-5f;

typedef _Float16 f16;
typedef f16 f16x2 __attribute__((ext_vector_type(2)));
typedef f16 f16x4 __attribute__((ext_vector_type(4)));
typedef f16 f16x8 __attribute__((ext_vector_type(8)));
typedef float f32x4 __attribute__((ext_vector_type(4)));
typedef __hip_bfloat16 bf16;

#define APAD 40   // f16 row stride (32 data + 8 pad) = 80B, 16B-aligned
#define BPAD 36   // f16 row stride = 72B

// ---------------------------------------------------------------------------
// Prep A: four C x C weight matrices -> hi/lo f16 planes (concatenated).
// ---------------------------------------------------------------------------
__global__ __launch_bounds__(256) void prep_w_kernel(
    const float* __restrict__ Wq, const float* __restrict__ Wk,
    const float* __restrict__ Wv, const float* __restrict__ Wt,
    f16* __restrict__ Whi, f16* __restrict__ Wlo)
{
    int idx = (blockIdx.x * 256 + threadIdx.x) * 8;   // over 4*C*C
    const float* s = (idx < 65536) ? Wq : (idx < 131072) ? Wk
                    : (idx < 196608) ? Wv : Wt;
    int off = idx & 65535;
    float4 a = *(const float4*)&s[off];
    float4 b = *(const float4*)&s[off + 4];
    float v[8] = {a.x, a.y, a.z, a.w, b.x, b.y, b.z, b.w};
    f16x8 h, l;
#pragma unroll
    for (int j = 0; j < 8; ++j) {
        f16 hh = (f16)v[j];
        f16 ll = (f16)(v[j] - (float)hh);
        h[j] = hh;
        l[j] = ll;
    }
    *(f16x8*)&Whi[idx] = h;
    *(f16x8*)&Wlo[idx] = l;
}

// ---------------------------------------------------------------------------
// Prep B: Xhi/Xlo[b][n][c] = split (f16) of x[b][c][n]  (LDS-tiled transpose)
// ---------------------------------------------------------------------------
__global__ __launch_bounds__(256) void prep_x_kernel(
    const float* __restrict__ x, f16* __restrict__ Xhi, f16* __restrict__ Xlo)
{
    const int b = blockIdx.z, c0 = blockIdx.y * 64, n0 = blockIdx.x * 64;
    const float* __restrict__ Xb = x + (size_t)b * CC * NN;
    f16* __restrict__ Oh = Xhi + (size_t)b * NN * CC;
    f16* __restrict__ Ol = Xlo + (size_t)b * NN * CC;
    __shared__ f16 Th[64][72];
    __shared__ f16 Tl[64][72];
    const int tid = threadIdx.x;
    const int r = tid >> 4, c4 = (tid & 15) * 4;
#pragma unroll
    for (int i = 0; i < 4; ++i) {
        int rr = r + i * 16;
        float4 v = *(const float4*)&Xb[(size_t)(c0 + rr) * NN + n0 + c4];
        float vv[4] = {v.x, v.y, v.z, v.w};
#pragma unroll
        for (int j = 0; j < 4; ++j) {
            f16 hh = (f16)vv[j];
            f16 ll = (f16)(vv[j] - (float)hh);
            Th[c4 + j][rr] = hh;
            Tl[c4 + j][rr] = ll;
        }
    }
    __syncthreads();
#pragma unroll
    for (int i = 0; i < 2; ++i) {
        int idx = tid + 256 * i;
        int n = idx >> 3, cg = (idx & 7) * 8;
        *(f16x8*)&Oh[(size_t)(n0 + n) * CC + c0 + cg] = *(f16x8*)&Th[n][cg];
        *(f16x8*)&Ol[(size_t)(n0 + n) * CC + c0 + cg] = *(f16x8*)&Tl[n][cg];
    }
}

// ---------------------------------------------------------------------------
// Kernel 1: projections via split-precision MFMA (hi*hi + hi*lo + lo*hi).
// which 0/1 -> Qhi/Qlo or Khi/Klo f16 planes [b][n][c] (split in epilogue);
// which 2 -> V16 f16 [b][c][n] (+bv).
// ---------------------------------------------------------------------------
__global__ __launch_bounds__(256) void proj_mfma_kernel(
    const f16* __restrict__ Whi, const f16* __restrict__ Wlo,
    const f16* __restrict__ Xhi, const f16* __restrict__ Xlo,
    const float* __restrict__ bv,
    f16* __restrict__ Qhi, f16* __restrict__ Qlo,
    f16* __restrict__ Khi, f16* __restrict__ Klo, f16* __restrict__ V16)
{
    const int which = blockIdx.z >> 3;
    const int b     = blockIdx.z & 7;
    const f16* __restrict__ Wh = Whi + (size_t)which * CC * CC;
    const f16* __restrict__ Wl = Wlo + (size_t)which * CC * CC;
    const f16* __restrict__ Xh = Xhi + (size_t)b * NN * CC;
    const f16* __restrict__ Xl = Xlo + (size_t)b * NN * CC;

    const int m0 = blockIdx.y * 128;   // output channels
    const int n0 = blockIdx.x * 128;   // points

    __shared__ f16 Ah[128 * APAD];
    __shared__ f16 Al[128 * APAD];
    __shared__ f16 Bh[128 * APAD];
    __shared__ f16 Bl[128 * APAD];

    const int tid = threadIdx.x;
    const int wave = tid >> 6, lane = tid & 63;
    const int wr = (wave >> 1) * 64, wc = (wave & 1) * 64;
    const int lrow = lane & 15, lk = (lane >> 4) * 8;

    f32x4 acc[4][4] = {};

    for (int k0 = 0; k0 < CC; k0 += 32) {
#pragma unroll
        for (int i = 0; i < 2; ++i) {
            int idx = tid + 256 * i;
            int r = idx >> 2, ch = idx & 3;
            *(f16x8*)&Ah[r * APAD + ch * 8] =
                *(const f16x8*)&Wh[(size_t)(m0 + r) * CC + k0 + ch * 8];
            *(f16x8*)&Al[r * APAD + ch * 8] =
                *(const f16x8*)&Wl[(size_t)(m0 + r) * CC + k0 + ch * 8];
            *(f16x8*)&Bh[r * APAD + ch * 8] =
                *(const f16x8*)&Xh[(size_t)(n0 + r) * CC + k0 + ch * 8];
            *(f16x8*)&Bl[r * APAD + ch * 8] =
                *(const f16x8*)&Xl[(size_t)(n0 + r) * CC + k0 + ch * 8];
        }
        __syncthreads();
        f16x8 ah[4], al[4], bh[4], bl[4];
#pragma unroll
        for (int i = 0; i < 4; ++i) {
            ah[i] = *(const f16x8*)&Ah[(wr + i * 16 + lrow) * APAD + lk];
            al[i] = *(const f16x8*)&Al[(wr + i * 16 + lrow) * APAD + lk];
            bh[i] = *(const f16x8*)&Bh[(wc + i * 16 + lrow) * APAD + lk];
            bl[i] = *(const f16x8*)&Bl[(wc + i * 16 + lrow) * APAD + lk];
        }
#pragma unroll
        for (int i = 0; i < 4; ++i)
#pragma unroll
            for (int j = 0; j < 4; ++j) {
                acc[i][j] = __builtin_amdgcn_mfma_f32_16x16x32_f16(
                    ah[i], bh[j], acc[i][j], 0, 0, 0);
                acc[i][j] = __builtin_amdgcn_mfma_f32_16x16x32_f16(
                    ah[i], bl[j], acc[i][j], 0, 0, 0);
                acc[i][j] = __builtin_amdgcn_mfma_f32_16x16x32_f16(
                    al[i], bh[j], acc[i][j], 0, 0, 0);
            }
        __syncthreads();
    }

    if (which < 2) {
        f16* __restrict__ Oh = ((which == 0) ? Qhi : Khi) + (size_t)b * NN * CC;
        f16* __restrict__ Ol = ((which == 0) ? Qlo : Klo) + (size_t)b * NN * CC;
#pragma unroll
        for (int i = 0; i < 4; ++i) {
            int cb = m0 + wr + i * 16 + (lane >> 4) * 4;
#pragma unroll
            for (int j = 0; j < 4; ++j) {
                int n = n0 + wc + j * 16 + lrow;
                f16x4 hv, lv;
#pragma unroll
                for (int q = 0; q < 4; ++q) {
                    float v = acc[i][j][q];
                    f16 hh = (f16)v;
                    hv[q] = hh;
                    lv[q] = (f16)(v - (float)hh);
                }
                *(f16x4*)&Oh[(size_t)n * CC + cb] = hv;
                *(f16x4*)&Ol[(size_t)n * CC + cb] = lv;
            }
        }
    } else {
        f16* __restrict__ Vb = V16 + (size_t)b * CC * NN;
#pragma unroll
        for (int i = 0; i < 4; ++i) {
            int cb = m0 + wr + i * 16 + (lane >> 4) * 4;
#pragma unroll
            for (int q = 0; q < 4; ++q) {
                float bvv = bv[cb + q];
#pragma unroll
                for (int j = 0; j < 4; ++j) {
                    int n = n0 + wc + j * 16 + lrow;
                    Vb[(size_t)(cb + q) * NN + n] = (f16)(acc[i][j][q] + bvv);
                }
            }
        }
    }
}

// ---------------------------------------------------------------------------
// Kernel 2: energy = Q . K^T from pre-split hi/lo planes -> fp32 logits.
// Pure-copy staging; no VALU split in the hot loop.
// ---------------------------------------------------------------------------
__global__ __launch_bounds__(256) void energy_mfma_kernel(
    const f16* __restrict__ Qhi, const f16* __restrict__ Qlo,
    const f16* __restrict__ Khi, const f16* __restrict__ Klo,
    float* __restrict__ ATT)
{
    const int b = blockIdx.z;
    const int n0 = blockIdx.y * 128;
    const int m0 = blockIdx.x * 128;
    const f16* __restrict__ Qh = Qhi + (size_t)b * NN * CC;
    const f16* __restrict__ Ql = Qlo + (size_t)b * NN * CC;
    const f16* __restrict__ Kh = Khi + (size_t)b * NN * CC;
    const f16* __restrict__ Kl = Klo + (size_t)b * NN * CC;
    float* __restrict__ Eb = ATT + (size_t)b * NN * NN;

    __shared__ f16 Ah[128 * APAD];
    __shared__ f16 Al[128 * APAD];
    __shared__ f16 Bh[128 * APAD];
    __shared__ f16 Bl[128 * APAD];

    const int tid = threadIdx.x;
    const int wave = tid >> 6, lane = tid & 63;
    const int wr = (wave >> 1) * 64, wc = (wave & 1) * 64;
    const int lrow = lane & 15, lk = (lane >> 4) * 8;

    f32x4 acc[4][4] = {};

    for (int k0 = 0; k0 < CC; k0 += 32) {
#pragma unroll
        for (int i = 0; i < 2; ++i) {
            int idx = tid + 256 * i;
            int r = idx >> 2, ch = idx & 3;
            *(f16x8*)&Ah[r * APAD + ch * 8] =
                *(const f16x8*)&Qh[(size_t)(n0 + r) * CC + k0 + ch * 8];
            *(f16x8*)&Al[r * APAD + ch * 8] =
                *(const f16x8*)&Ql[(size_t)(n0 + r) * CC + k0 + ch * 8];
            *(f16x8*)&Bh[r * APAD + ch * 8] =
                *(const f16x8*)&Kh[(size_t)(m0 + r) * CC + k0 + ch * 8];
            *(f16x8*)&Bl[r * APAD + ch * 8] =
                *(const f16x8*)&Kl[(size_t)(m0 + r) * CC + k0 + ch * 8];
        }
        __syncthreads();
        f16x8 ah[4], al[4], bh[4], bl[4];
#pragma unroll
        for (int i = 0; i < 4; ++i) {
            ah[i] = *(const f16x8*)&Ah[(wr + i * 16 + lrow) * APAD + lk];
            al[i] = *(const f16x8*)&Al[(wr + i * 16 + lrow) * APAD + lk];
            bh[i] = *(const f16x8*)&Bh[(wc + i * 16 + lrow) * APAD + lk];
            bl[i] = *(const f16x8*)&Bl[(wc + i * 16 + lrow) * APAD + lk];
        }
#pragma unroll
        for (int i = 0; i < 4; ++i)
#pragma unroll
            for (int j = 0; j < 4; ++j) {
                acc[i][j] = __builtin_amdgcn_mfma_f32_16x16x32_f16(
                    ah[i], bh[j], acc[i][j], 0, 0, 0);
                acc[i][j] = __builtin_amdgcn_mfma_f32_16x16x32_f16(
                    ah[i], bl[j], acc[i][j], 0, 0, 0);
                acc[i][j] = __builtin_amdgcn_mfma_f32_16x16x32_f16(
                    al[i], bh[j], acc[i][j], 0, 0, 0);
            }
        __syncthreads();
    }

#pragma unroll
    for (int i = 0; i < 4; ++i)
#pragma unroll
        for (int q = 0; q < 4; ++q) {
            int row = n0 + wr + i * 16 + (lane >> 4) * 4 + q;
#pragma unroll
            for (int j = 0; j < 4; ++j) {
                int col = m0 + wc + j * 16 + lrow;
                Eb[(size_t)row * NN + col] = acc[i][j][q];
            }
        }
}

// ---------------------------------------------------------------------------
// Kernel 3: row softmax; fp32 logits in, normalized bf16 out IN PLACE
// (packed at the row start; bf16 row stride = 2*NN). bf16 keeps fp32's
// exponent range, so tiny columns survive the later double-normalization.
// ---------------------------------------------------------------------------
__global__ __launch_bounds__(256) void softmax_kernel(float* __restrict__ ATT)
{
    const size_t row = blockIdx.x;
    float* __restrict__ R = ATT + row * NN;
    const int tid = threadIdx.x;
    const int wave = tid >> 6, lane = tid & 63;

    float e[8];
#pragma unroll
    for (int j = 0; j < 8; ++j) e[j] = R[tid + 256 * j];

    float mx = e[0];
#pragma unroll
    for (int j = 1; j < 8; ++j) mx = fmaxf(mx, e[j]);
#pragma unroll
    for (int s = 1; s < 64; s <<= 1) mx = fmaxf(mx, __shfl_xor(mx, s));

    __shared__ float redm[4];
    if (lane == 0) redm[wave] = mx;
    __syncthreads();
    mx = fmaxf(fmaxf(redm[0], redm[1]), fmaxf(redm[2], redm[3]));

    float s = 0.f;
#pragma unroll
    for (int j = 0; j < 8; ++j) { e[j] = __expf(e[j] - mx); s += e[j]; }
#pragma unroll
    for (int t = 1; t < 64; t <<= 1) s += __shfl_xor(s, t);

    __shared__ float reds[4];
    if (lane == 0) reds[wave] = s;
    __syncthreads();
    s = reds[0] + reds[1] + reds[2] + reds[3];

    const float inv = 1.f / s;
    bf16* __restrict__ R16 = (bf16*)R;
#pragma unroll
    for (int j = 0; j < 8; ++j)
        R16[tid + 256 * j] = __float2bfloat16(e[j] * inv);
}

// ---------------------------------------------------------------------------
// Kernel 4: column sums over bf16 attention
// ---------------------------------------------------------------------------
__global__ __launch_bounds__(256) void colsum_kernel(
    const float* __restrict__ ATT, float* __restrict__ colsum)
{
    const int b = blockIdx.z;
    const int m = blockIdx.x * 256 + threadIdx.x;
    const int n0 = blockIdx.y * 128;
    const bf16* __restrict__ Ab16 = (const bf16*)(ATT + (size_t)b * NN * NN);
    float s = 0.f;
    for (int n = n0; n < n0 + 128; ++n)
        s += __bfloat162float(Ab16[(size_t)n * (2 * NN) + m]);
    atomicAdd(&colsum[b * NN + m], s);
}

// ---------------------------------------------------------------------------
// Kernel 5: x_r = V16 * (ATT_bf16*diag(rcv)); Dt16[n][c] = (f16)(x - x_r)
// f16 conversion happens AFTER the rcv scale (range-safe).
// ---------------------------------------------------------------------------
__global__ __launch_bounds__(256) void xr_mfma_kernel(
    const f16* __restrict__ V16, const float* __restrict__ ATT,
    const float* __restrict__ colsum, const float* __restrict__ x,
    f16* __restrict__ Dt16)
{
    const int b  = blockIdx.z;
    const int c0 = blockIdx.y * 128;
    const int m0 = blockIdx.x * 128;
    const f16* __restrict__ Vb = V16 + (size_t)b * CC * NN;
    const bf16* __restrict__ Ab16 = (const bf16*)(ATT + (size_t)b * NN * NN);
    const float* __restrict__ Xb = x + (size_t)b * CC * NN;
    f16* __restrict__ Db = Dt16 + (size_t)b * NN * CC;

    __shared__ f16 Asl[128 * APAD];
    __shared__ f16 Bsl[128 * BPAD];
    __shared__ float rcv[128];

    const int tid = threadIdx.x;
    if (tid < 128) rcv[tid] = 1.f / (1e-9f + colsum[b * NN + m0 + tid]);
    __syncthreads();

    const int wave = tid >> 6, lane = tid & 63;
    const int wr = (wave >> 1) * 64, wc = (wave & 1) * 64;
    const int lrow = lane & 15, lk = (lane >> 4) * 8;

    f32x4 acc[4][4] = {};

    for (int k0 = 0; k0 < NN; k0 += 32) {
#pragma unroll
        for (int i = 0; i < 2; ++i) {
            int idx = tid + 256 * i;
            int r = idx >> 2, ch = idx & 3;
            *(f16x8*)&Asl[r * APAD + ch * 8] =
                *(const f16x8*)&Vb[(size_t)(c0 + r) * NN + k0 + ch * 8];
        }
#pragma unroll
        for (int i = 0; i < 8; ++i) {
            int idx = tid + 256 * i;
            int m = idx & 127, np = idx >> 7;
            int n = k0 + np * 2;
            float sc = rcv[m];
            float a0 = __bfloat162float(Ab16[(size_t)n * (2 * NN) + m0 + m]) * sc;
            float a1 = __bfloat162float(Ab16[(size_t)(n + 1) * (2 * NN) + m0 + m]) * sc;
            f16x2 p = {(f16)a0, (f16)a1};
            *(f16x2*)&Bsl[m * BPAD + np * 2] = p;
        }
        __syncthreads();
        f16x8 af[4], bf[4];
#pragma unroll
        for (int i = 0; i < 4; ++i) {
            af[i] = *(const f16x8*)&Asl[(wr + i * 16 + lrow) * APAD + lk];
            f16x4 lo = *(const f16x4*)&Bsl[(wc + i * 16 + lrow) * BPAD + lk];
            f16x4 hi = *(const f16x4*)&Bsl[(wc + i * 16 + lrow) * BPAD + lk + 4];
            f16x8 bb;
            bb[0] = lo[0]; bb[1] = lo[1]; bb[2] = lo[2]; bb[3] = lo[3];
            bb[4] = hi[0]; bb[5] = hi[1]; bb[6] = hi[2]; bb[7] = hi[3];
            bf[i] = bb;
        }
#pragma unroll
        for (int i = 0; i < 4; ++i)
#pragma unroll
            for (int j = 0; j < 4; ++j)
                acc[i][j] = __builtin_amdgcn_mfma_f32_16x16x32_f16(
                    af[i], bf[j], acc[i][j], 0, 0, 0);
        __syncthreads();
    }

#pragma unroll
    for (int i = 0; i < 4; ++i) {
        int cb = c0 + wr + i * 16 + (lane >> 4) * 4;
#pragma unroll
        for (int j = 0; j < 4; ++j) {
            int n = m0 + wc + j * 16 + lrow;
            f16x4 dv;
#pragma unroll
            for (int q = 0; q < 4; ++q)
                dv[q] = (f16)(Xb[(size_t)(cb + q) * NN + n] - acc[i][j][q]);
            *(f16x4*)&Db[(size_t)n * CC + cb] = dv;
        }
    }
}

// ---------------------------------------------------------------------------
// Kernel 6: XZ(bf16) = alpha*(Wt*Dt16 + bt) + beta; BN sums from fp32 values.
// ---------------------------------------------------------------------------
__global__ __launch_bounds__(256) void xz_mfma_kernel(
    const f16* __restrict__ Whi, const f16* __restrict__ Dt16,
    const float* __restrict__ bt, const float* __restrict__ alpha,
    const float* __restrict__ beta, bf16* __restrict__ XZ,
    float* __restrict__ bnsum, float* __restrict__ bnsumsq)
{
    const int b = blockIdx.z;
    const int m0 = blockIdx.y * 128;
    const int n0 = blockIdx.x * 128;
    const f16* __restrict__ Wb = Whi + (size_t)3 * CC * CC;   // Wt (hi)
    const f16* __restrict__ Db = Dt16 + (size_t)b * NN * CC;
    bf16* __restrict__ Zb = XZ + (size_t)b * CC * NN;

    __shared__ f16 Asl[128 * APAD];
    __shared__ f16 Bsl[128 * APAD];

    const int tid = threadIdx.x;
    const int wave = tid >> 6, lane = tid & 63;
    const int wr = (wave >> 1) * 64, wc = (wave & 1) * 64;
    const int lrow = lane & 15, lk = (lane >> 4) * 8;

    f32x4 acc[4][4] = {};

    for (int k0 = 0; k0 < CC; k0 += 32) {
#pragma unroll
        for (int i = 0; i < 2; ++i) {
            int idx = tid + 256 * i;
            int r = idx >> 2, ch = idx & 3;
            *(f16x8*)&Asl[r * APAD + ch * 8] =
                *(const f16x8*)&Wb[(size_t)(m0 + r) * CC + k0 + ch * 8];
            *(f16x8*)&Bsl[r * APAD + ch * 8] =
                *(const f16x8*)&Db[(size_t)(n0 + r) * CC + k0 + ch * 8];
        }
        __syncthreads();
        f16x8 af[4], bf[4];
#pragma unroll
        for (int i = 0; i < 4; ++i) {
            af[i] = *(const f16x8*)&Asl[(wr + i * 16 + lrow) * APAD + lk];
            bf[i] = *(const f16x8*)&Bsl[(wc + i * 16 + lrow) * APAD + lk];
        }
#pragma unroll
        for (int i = 0; i < 4; ++i)
#pragma unroll
            for (int j = 0; j < 4; ++j)
                acc[i][j] = __builtin_amdgcn_mfma_f32_16x16x32_f16(
                    af[i], bf[j], acc[i][j], 0, 0, 0);
        __syncthreads();
    }

#pragma unroll
    for (int i = 0; i < 4; ++i) {
#pragma unroll
        for (int q = 0; q < 4; ++q) {
            int o = m0 + wr + i * 16 + (lane >> 4) * 4 + q;
            float al = alpha[o], be = beta[o], bb = bt[o];
            float s1 = 0.f, s2 = 0.f;
#pragma unroll
            for (int j = 0; j < 4; ++j) {
                int n = n0 + wc + j * 16 + lrow;
                float z = al * (acc[i][j][q] + bb) + be;
                Zb[(size_t)o * NN + n] = __float2bfloat16(z);
                s1 += z; s2 += z * z;
            }
#pragma unroll
            for (int d = 1; d < 16; d <<= 1) {
                s1 += __shfl_xor(s1, d);
                s2 += __shfl_xor(s2, d);
            }
            if (lrow == 0) {
                atomicAdd(&bnsum[o], s1);
                atomicAdd(&bnsumsq[o], s2);
            }
        }
    }
}

// ---------------------------------------------------------------------------
// Kernel 7: out = x + relu(gamma*(XZ-mean)*rsqrt(var+eps)+beta)
// ---------------------------------------------------------------------------
__global__ __launch_bounds__(256) void final_kernel(
    const float* __restrict__ x, const bf16* __restrict__ XZ,
    const float* __restrict__ bnsum, const float* __restrict__ bnsumsq,
    const float* __restrict__ gamma, const float* __restrict__ bbeta,
    float* __restrict__ out)
{
    const int i4 = blockIdx.x * 256 + threadIdx.x;
    const int elem = i4 * 4;
    const int c = (elem / NN) % CC;
    const float inv_cnt = 1.f / (float)(BB * NN);
    const float mean = bnsum[c] * inv_cnt;
    const float var  = bnsumsq[c] * inv_cnt - mean * mean;
    const float rs = rsqrtf(var + BN_EPS);
    const float g = gamma[c], bb = bbeta[c];

    ushort4 zu = *(const ushort4*)&XZ[elem];
    float4 xv = *(const float4*)&x[elem];
    float z0 = __uint_as_float((unsigned)zu.x << 16);
    float z1 = __uint_as_float((unsigned)zu.y << 16);
    float z2 = __uint_as_float((unsigned)zu.z << 16);
    float z3 = __uint_as_float((unsigned)zu.w << 16);
    float4 o;
    o.x = xv.x + fmaxf(g * (z0 - mean) * rs + bb, 0.f);
    o.y = xv.y + fmaxf(g * (z1 - mean) * rs + bb, 0.f);
    o.z = xv.z + fmaxf(g * (z2 - mean) * rs + bb, 0.f);
    o.w = xv.w + fmaxf(g * (z3 - mean) * rs + bb, 0.f);
    *(float4*)&out[elem] = o;
}

// ---------------------------------------------------------------------------

extern "C" void kernel_launch(void* const* d_in, const int* in_sizes, int n_in,
                              void* d_out, int out_size, void* d_ws, size_t ws_size,
                              hipStream_t stream) {
    const float* x     = (const float*)d_in[0];
    const float* Wq    = (const float*)d_in[1];
    const float* Wk    = (const float*)d_in[2];
    const float* Wv    = (const float*)d_in[3];
    const float* bv    = (const float*)d_in[4];
    const float* Wt    = (const float*)d_in[5];
    const float* bt    = (const float*)d_in[6];
    const float* gamma = (const float*)d_in[7];
    const float* bbeta = (const float*)d_in[8];
    const float* alpha = (const float*)d_in[9];
    const float* beta  = (const float*)d_in[10];
    float* out = (float*)d_out;

    const size_t BCN = (size_t)BB * CC * NN;   // 4,194,304 elements
    const size_t WSZ = (size_t)4 * CC * CC;    // 262,144

    f16* Whi = (f16*)d_ws;                     // 4 x [C][C] hi
    f16* Wlo = Whi + WSZ;                      // 4 x [C][C] lo
    f16* V16 = Wlo + WSZ;                      // [B][C][N]
    f16* Qhi = V16 + BCN;                      // [B][N][C]
    f16* Qlo = Qhi + BCN;
    f16* Khi = Qlo + BCN;
    f16* Klo = Khi + BCN;
    float* ATT = (float*)(Klo + BCN);          // [B][N][N] fp32 logits / bf16 attn
    bf16* XZ = (bf16*)(ATT + (size_t)BB * NN * NN);  // [B][C][N] bf16
    float* colsum  = (float*)(XZ + BCN);       // [B][N]
    float* bnsum   = colsum + (size_t)BB * NN; // [C]
    float* bnsumsq = bnsum + CC;               // [C]

    // Xhi/Xlo overlay batch-0's ATT slab (dead by the time energy writes it).
    f16* Xhi = (f16*)ATT;                      // [B][N][C]
    f16* Xlo = Xhi + BCN;                      // [B][N][C]
    f16* Dt16 = Qhi;                           // reuse Qhi after energy

    hipMemsetAsync(colsum, 0, (size_t)(BB * NN + 2 * CC) * sizeof(float), stream);

    prep_w_kernel<<<dim3(4 * CC * CC / 2048), 256, 0, stream>>>(
        Wq, Wk, Wv, Wt, Whi, Wlo);
    prep_x_kernel<<<dim3(NN / 64, CC / 64, BB), 256, 0, stream>>>(x, Xhi, Xlo);
    proj_mfma_kernel<<<dim3(NN / 128, CC / 128, 3 * BB), 256, 0, stream>>>(
        Whi, Wlo, Xhi, Xlo, bv, Qhi, Qlo, Khi, Klo, V16);
    energy_mfma_kernel<<<dim3(NN / 128, NN / 128, BB), 256, 0, stream>>>(
        Qhi, Qlo, Khi, Klo, ATT);
    softmax_kernel<<<dim3(BB * NN), 256, 0, stream>>>(ATT);
    colsum_kernel<<<dim3(NN / 256, 16, BB), 256, 0, stream>>>(ATT, colsum);
    xr_mfma_kernel<<<dim3(NN / 128, CC / 128, BB), 256, 0, stream>>>(
        V16, ATT, colsum, x, Dt16);
    xz_mfma_kernel<<<dim3(NN / 128, CC / 128, BB), 256, 0, stream>>>(
        Whi, Dt16, bt, alpha, beta, XZ, bnsum, bnsumsq);
    final_kernel<<<dim3((int)(BCN / 4 / 256)), 256, 0, stream>>>(
        x, XZ, bnsum, bnsumsq, gamma, bbeta, out);
}

// Round 8
// 271.525 us; speedup vs baseline: 2.6193x; 1.0211x over previous
//
#include <hip/hip_runtime.h>
#include <hip/hip_bf16.h>
#include <math.h>

#define BB 8
#define CC 256
#define NN 2048
static constexpr float BN_EPS = 1e-5f;

typedef _Float16 f16;
typedef f16 f16x2 __attribute__((ext_vector_type(2)));
typedef f16 f16x4 __attribute__((ext_vector_type(4)));
typedef f16 f16x8 __attribute__((ext_vector_type(8)));
typedef float f32x4 __attribute__((ext_vector_type(4)));
typedef __hip_bfloat16 bf16;

#define APAD 40   // f16 row stride (32 data + 8 pad) = 80B, 16B-aligned
#define BPAD 36   // f16 row stride = 72B

// ---------------------------------------------------------------------------
// Prep A: four C x C weight matrices -> hi/lo f16 planes (concatenated).
// ---------------------------------------------------------------------------
__global__ __launch_bounds__(256) void prep_w_kernel(
    const float* __restrict__ Wq, const float* __restrict__ Wk,
    const float* __restrict__ Wv, const float* __restrict__ Wt,
    f16* __restrict__ Whi, f16* __restrict__ Wlo)
{
    int idx = (blockIdx.x * 256 + threadIdx.x) * 8;   // over 4*C*C
    const float* s = (idx < 65536) ? Wq : (idx < 131072) ? Wk
                    : (idx < 196608) ? Wv : Wt;
    int off = idx & 65535;
    float4 a = *(const float4*)&s[off];
    float4 b = *(const float4*)&s[off + 4];
    float v[8] = {a.x, a.y, a.z, a.w, b.x, b.y, b.z, b.w};
    f16x8 h, l;
#pragma unroll
    for (int j = 0; j < 8; ++j) {
        f16 hh = (f16)v[j];
        f16 ll = (f16)(v[j] - (float)hh);
        h[j] = hh;
        l[j] = ll;
    }
    *(f16x8*)&Whi[idx] = h;
    *(f16x8*)&Wlo[idx] = l;
}

// ---------------------------------------------------------------------------
// Prep B: Xhi/Xlo[b][n][c] = split (f16) of x[b][c][n]  (LDS-tiled transpose)
// ---------------------------------------------------------------------------
__global__ __launch_bounds__(256) void prep_x_kernel(
    const float* __restrict__ x, f16* __restrict__ Xhi, f16* __restrict__ Xlo)
{
    const int b = blockIdx.z, c0 = blockIdx.y * 64, n0 = blockIdx.x * 64;
    const float* __restrict__ Xb = x + (size_t)b * CC * NN;
    f16* __restrict__ Oh = Xhi + (size_t)b * NN * CC;
    f16* __restrict__ Ol = Xlo + (size_t)b * NN * CC;
    __shared__ f16 Th[64][72];
    __shared__ f16 Tl[64][72];
    const int tid = threadIdx.x;
    const int r = tid >> 4, c4 = (tid & 15) * 4;
#pragma unroll
    for (int i = 0; i < 4; ++i) {
        int rr = r + i * 16;
        float4 v = *(const float4*)&Xb[(size_t)(c0 + rr) * NN + n0 + c4];
        float vv[4] = {v.x, v.y, v.z, v.w};
#pragma unroll
        for (int j = 0; j < 4; ++j) {
            f16 hh = (f16)vv[j];
            f16 ll = (f16)(vv[j] - (float)hh);
            Th[c4 + j][rr] = hh;
            Tl[c4 + j][rr] = ll;
        }
    }
    __syncthreads();
#pragma unroll
    for (int i = 0; i < 2; ++i) {
        int idx = tid + 256 * i;
        int n = idx >> 3, cg = (idx & 7) * 8;
        *(f16x8*)&Oh[(size_t)(n0 + n) * CC + c0 + cg] = *(f16x8*)&Th[n][cg];
        *(f16x8*)&Ol[(size_t)(n0 + n) * CC + c0 + cg] = *(f16x8*)&Tl[n][cg];
    }
}

// ---------------------------------------------------------------------------
// Kernel 1: projections via split-precision MFMA (hi*hi + hi*lo + lo*hi).
// which 0/1 -> Qhi/Khi f16 [b][n][c] (f16-rounded from fp32-accurate acc);
// which 2 -> V16 f16 [b][c][n] (+bv).
// ---------------------------------------------------------------------------
__global__ __launch_bounds__(256) void proj_mfma_kernel(
    const f16* __restrict__ Whi, const f16* __restrict__ Wlo,
    const f16* __restrict__ Xhi, const f16* __restrict__ Xlo,
    const float* __restrict__ bv,
    f16* __restrict__ Qhi, f16* __restrict__ Khi, f16* __restrict__ V16)
{
    const int which = blockIdx.z >> 3;
    const int b     = blockIdx.z & 7;
    const f16* __restrict__ Wh = Whi + (size_t)which * CC * CC;
    const f16* __restrict__ Wl = Wlo + (size_t)which * CC * CC;
    const f16* __restrict__ Xh = Xhi + (size_t)b * NN * CC;
    const f16* __restrict__ Xl = Xlo + (size_t)b * NN * CC;

    const int m0 = blockIdx.y * 128;   // output channels
    const int n0 = blockIdx.x * 128;   // points

    __shared__ f16 Ah[128 * APAD];
    __shared__ f16 Al[128 * APAD];
    __shared__ f16 Bh[128 * APAD];
    __shared__ f16 Bl[128 * APAD];

    const int tid = threadIdx.x;
    const int wave = tid >> 6, lane = tid & 63;
    const int wr = (wave >> 1) * 64, wc = (wave & 1) * 64;
    const int lrow = lane & 15, lk = (lane >> 4) * 8;

    f32x4 acc[4][4] = {};

    for (int k0 = 0; k0 < CC; k0 += 32) {
#pragma unroll
        for (int i = 0; i < 2; ++i) {
            int idx = tid + 256 * i;
            int r = idx >> 2, ch = idx & 3;
            *(f16x8*)&Ah[r * APAD + ch * 8] =
                *(const f16x8*)&Wh[(size_t)(m0 + r) * CC + k0 + ch * 8];
            *(f16x8*)&Al[r * APAD + ch * 8] =
                *(const f16x8*)&Wl[(size_t)(m0 + r) * CC + k0 + ch * 8];
            *(f16x8*)&Bh[r * APAD + ch * 8] =
                *(const f16x8*)&Xh[(size_t)(n0 + r) * CC + k0 + ch * 8];
            *(f16x8*)&Bl[r * APAD + ch * 8] =
                *(const f16x8*)&Xl[(size_t)(n0 + r) * CC + k0 + ch * 8];
        }
        __syncthreads();
        f16x8 ah[4], al[4], bh[4], bl[4];
#pragma unroll
        for (int i = 0; i < 4; ++i) {
            ah[i] = *(const f16x8*)&Ah[(wr + i * 16 + lrow) * APAD + lk];
            al[i] = *(const f16x8*)&Al[(wr + i * 16 + lrow) * APAD + lk];
            bh[i] = *(const f16x8*)&Bh[(wc + i * 16 + lrow) * APAD + lk];
            bl[i] = *(const f16x8*)&Bl[(wc + i * 16 + lrow) * APAD + lk];
        }
#pragma unroll
        for (int i = 0; i < 4; ++i)
#pragma unroll
            for (int j = 0; j < 4; ++j) {
                acc[i][j] = __builtin_amdgcn_mfma_f32_16x16x32_f16(
                    ah[i], bh[j], acc[i][j], 0, 0, 0);
                acc[i][j] = __builtin_amdgcn_mfma_f32_16x16x32_f16(
                    ah[i], bl[j], acc[i][j], 0, 0, 0);
                acc[i][j] = __builtin_amdgcn_mfma_f32_16x16x32_f16(
                    al[i], bh[j], acc[i][j], 0, 0, 0);
            }
        __syncthreads();
    }

    if (which < 2) {
        f16* __restrict__ Oh = ((which == 0) ? Qhi : Khi) + (size_t)b * NN * CC;
#pragma unroll
        for (int i = 0; i < 4; ++i) {
            int cb = m0 + wr + i * 16 + (lane >> 4) * 4;
#pragma unroll
            for (int j = 0; j < 4; ++j) {
                int n = n0 + wc + j * 16 + lrow;
                f16x4 hv;
#pragma unroll
                for (int q = 0; q < 4; ++q) hv[q] = (f16)acc[i][j][q];
                *(f16x4*)&Oh[(size_t)n * CC + cb] = hv;
            }
        }
    } else {
        f16* __restrict__ Vb = V16 + (size_t)b * CC * NN;
#pragma unroll
        for (int i = 0; i < 4; ++i) {
            int cb = m0 + wr + i * 16 + (lane >> 4) * 4;
#pragma unroll
            for (int q = 0; q < 4; ++q) {
                float bvv = bv[cb + q];
#pragma unroll
                for (int j = 0; j < 4; ++j) {
                    int n = n0 + wc + j * 16 + lrow;
                    Vb[(size_t)(cb + q) * NN + n] = (f16)(acc[i][j][q] + bvv);
                }
            }
        }
    }
}

// ---------------------------------------------------------------------------
// Kernel 2: energy = Qhi . Khi^T -> fp32 logits. Direct-global MFMA
// fragments: no LDS, no barriers, no bank conflicts. Q/K panels are
// L2-resident (16 MB total) and reused 16x across blocks.
// ---------------------------------------------------------------------------
__global__ __launch_bounds__(256) void energy_mfma_kernel(
    const f16* __restrict__ Qhi, const f16* __restrict__ Khi,
    float* __restrict__ ATT)
{
    const int b = blockIdx.z;
    const int n0 = blockIdx.y * 128;
    const int m0 = blockIdx.x * 128;
    const f16* __restrict__ Qh = Qhi + (size_t)b * NN * CC;
    const f16* __restrict__ Kh = Khi + (size_t)b * NN * CC;
    float* __restrict__ Eb = ATT + (size_t)b * NN * NN;

    const int tid = threadIdx.x;
    const int wave = tid >> 6, lane = tid & 63;
    const int wr = (wave >> 1) * 64, wc = (wave & 1) * 64;
    const int lrow = lane & 15, lk = (lane >> 4) * 8;

    const f16* __restrict__ qb = &Qh[(size_t)(n0 + wr + lrow) * CC + lk];
    const f16* __restrict__ kb = &Kh[(size_t)(m0 + wc + lrow) * CC + lk];

    f32x4 acc[4][4] = {};

#pragma unroll
    for (int k0 = 0; k0 < CC; k0 += 32) {
        f16x8 af[4], bf[4];
#pragma unroll
        for (int i = 0; i < 4; ++i) {
            af[i] = *(const f16x8*)&qb[(size_t)(i * 16) * CC + k0];
            bf[i] = *(const f16x8*)&kb[(size_t)(i * 16) * CC + k0];
        }
#pragma unroll
        for (int i = 0; i < 4; ++i)
#pragma unroll
            for (int j = 0; j < 4; ++j)
                acc[i][j] = __builtin_amdgcn_mfma_f32_16x16x32_f16(
                    af[i], bf[j], acc[i][j], 0, 0, 0);
    }

#pragma unroll
    for (int i = 0; i < 4; ++i)
#pragma unroll
        for (int q = 0; q < 4; ++q) {
            int row = n0 + wr + i * 16 + (lane >> 4) * 4 + q;
#pragma unroll
            for (int j = 0; j < 4; ++j) {
                int col = m0 + wc + j * 16 + lrow;
                Eb[(size_t)row * NN + col] = acc[i][j][q];
            }
        }
}

// ---------------------------------------------------------------------------
// Kernel 3: row softmax; fp32 logits in, normalized bf16 out IN PLACE
// (packed at the row start; bf16 row stride = 2*NN). bf16 keeps fp32's
// exponent range, so tiny columns survive the later double-normalization.
// ---------------------------------------------------------------------------
__global__ __launch_bounds__(256) void softmax_kernel(float* __restrict__ ATT)
{
    const size_t row = blockIdx.x;
    float* __restrict__ R = ATT + row * NN;
    const int tid = threadIdx.x;
    const int wave = tid >> 6, lane = tid & 63;

    float e[8];
#pragma unroll
    for (int j = 0; j < 8; ++j) e[j] = R[tid + 256 * j];

    float mx = e[0];
#pragma unroll
    for (int j = 1; j < 8; ++j) mx = fmaxf(mx, e[j]);
#pragma unroll
    for (int s = 1; s < 64; s <<= 1) mx = fmaxf(mx, __shfl_xor(mx, s));

    __shared__ float redm[4];
    if (lane == 0) redm[wave] = mx;
    __syncthreads();
    mx = fmaxf(fmaxf(redm[0], redm[1]), fmaxf(redm[2], redm[3]));

    float s = 0.f;
#pragma unroll
    for (int j = 0; j < 8; ++j) { e[j] = __expf(e[j] - mx); s += e[j]; }
#pragma unroll
    for (int t = 1; t < 64; t <<= 1) s += __shfl_xor(s, t);

    __shared__ float reds[4];
    if (lane == 0) reds[wave] = s;
    __syncthreads();
    s = reds[0] + reds[1] + reds[2] + reds[3];

    const float inv = 1.f / s;
    bf16* __restrict__ R16 = (bf16*)R;
#pragma unroll
    for (int j = 0; j < 8; ++j)
        R16[tid + 256 * j] = __float2bfloat16(e[j] * inv);
}

// ---------------------------------------------------------------------------
// Kernel 4: column sums over bf16 attention
// ---------------------------------------------------------------------------
__global__ __launch_bounds__(256) void colsum_kernel(
    const float* __restrict__ ATT, float* __restrict__ colsum)
{
    const int b = blockIdx.z;
    const int m = blockIdx.x * 256 + threadIdx.x;
    const int n0 = blockIdx.y * 128;
    const bf16* __restrict__ Ab16 = (const bf16*)(ATT + (size_t)b * NN * NN);
    float s = 0.f;
    for (int n = n0; n < n0 + 128; ++n)
        s += __bfloat162float(Ab16[(size_t)n * (2 * NN) + m]);
    atomicAdd(&colsum[b * NN + m], s);
}

// ---------------------------------------------------------------------------
// Kernel 5: x_r = V16 * (ATT_bf16*diag(rcv)); Dt16[n][c] = (f16)(x - x_r)
// f16 conversion happens AFTER the rcv scale (range-safe).
// ---------------------------------------------------------------------------
__global__ __launch_bounds__(256) void xr_mfma_kernel(
    const f16* __restrict__ V16, const float* __restrict__ ATT,
    const float* __restrict__ colsum, const float* __restrict__ x,
    f16* __restrict__ Dt16)
{
    const int b  = blockIdx.z;
    const int c0 = blockIdx.y * 128;
    const int m0 = blockIdx.x * 128;
    const f16* __restrict__ Vb = V16 + (size_t)b * CC * NN;
    const bf16* __restrict__ Ab16 = (const bf16*)(ATT + (size_t)b * NN * NN);
    const float* __restrict__ Xb = x + (size_t)b * CC * NN;
    f16* __restrict__ Db = Dt16 + (size_t)b * NN * CC;

    __shared__ f16 Asl[128 * APAD];
    __shared__ f16 Bsl[128 * BPAD];
    __shared__ float rcv[128];

    const int tid = threadIdx.x;
    if (tid < 128) rcv[tid] = 1.f / (1e-9f + colsum[b * NN + m0 + tid]);
    __syncthreads();

    const int wave = tid >> 6, lane = tid & 63;
    const int wr = (wave >> 1) * 64, wc = (wave & 1) * 64;
    const int lrow = lane & 15, lk = (lane >> 4) * 8;

    f32x4 acc[4][4] = {};

    for (int k0 = 0; k0 < NN; k0 += 32) {
#pragma unroll
        for (int i = 0; i < 2; ++i) {
            int idx = tid + 256 * i;
            int r = idx >> 2, ch = idx & 3;
            *(f16x8*)&Asl[r * APAD + ch * 8] =
                *(const f16x8*)&Vb[(size_t)(c0 + r) * NN + k0 + ch * 8];
        }
#pragma unroll
        for (int i = 0; i < 8; ++i) {
            int idx = tid + 256 * i;
            int m = idx & 127, np = idx >> 7;
            int n = k0 + np * 2;
            float sc = rcv[m];
            float a0 = __bfloat162float(Ab16[(size_t)n * (2 * NN) + m0 + m]) * sc;
            float a1 = __bfloat162float(Ab16[(size_t)(n + 1) * (2 * NN) + m0 + m]) * sc;
            f16x2 p = {(f16)a0, (f16)a1};
            *(f16x2*)&Bsl[m * BPAD + np * 2] = p;
        }
        __syncthreads();
        f16x8 af[4], bf[4];
#pragma unroll
        for (int i = 0; i < 4; ++i) {
            af[i] = *(const f16x8*)&Asl[(wr + i * 16 + lrow) * APAD + lk];
            f16x4 lo = *(const f16x4*)&Bsl[(wc + i * 16 + lrow) * BPAD + lk];
            f16x4 hi = *(const f16x4*)&Bsl[(wc + i * 16 + lrow) * BPAD + lk + 4];
            f16x8 bb;
            bb[0] = lo[0]; bb[1] = lo[1]; bb[2] = lo[2]; bb[3] = lo[3];
            bb[4] = hi[0]; bb[5] = hi[1]; bb[6] = hi[2]; bb[7] = hi[3];
            bf[i] = bb;
        }
#pragma unroll
        for (int i = 0; i < 4; ++i)
#pragma unroll
            for (int j = 0; j < 4; ++j)
                acc[i][j] = __builtin_amdgcn_mfma_f32_16x16x32_f16(
                    af[i], bf[j], acc[i][j], 0, 0, 0);
        __syncthreads();
    }

#pragma unroll
    for (int i = 0; i < 4; ++i) {
        int cb = c0 + wr + i * 16 + (lane >> 4) * 4;
#pragma unroll
        for (int j = 0; j < 4; ++j) {
            int n = m0 + wc + j * 16 + lrow;
            f16x4 dv;
#pragma unroll
            for (int q = 0; q < 4; ++q)
                dv[q] = (f16)(Xb[(size_t)(cb + q) * NN + n] - acc[i][j][q]);
            *(f16x4*)&Db[(size_t)n * CC + cb] = dv;
        }
    }
}

// ---------------------------------------------------------------------------
// Kernel 6: XZ(bf16) = alpha*(Wt*Dt16 + bt) + beta; BN sums from fp32 values.
// ---------------------------------------------------------------------------
__global__ __launch_bounds__(256) void xz_mfma_kernel(
    const f16* __restrict__ Whi, const f16* __restrict__ Dt16,
    const float* __restrict__ bt, const float* __restrict__ alpha,
    const float* __restrict__ beta, bf16* __restrict__ XZ,
    float* __restrict__ bnsum, float* __restrict__ bnsumsq)
{
    const int b = blockIdx.z;
    const int m0 = blockIdx.y * 128;
    const int n0 = blockIdx.x * 128;
    const f16* __restrict__ Wb = Whi + (size_t)3 * CC * CC;   // Wt (hi)
    const f16* __restrict__ Db = Dt16 + (size_t)b * NN * CC;
    bf16* __restrict__ Zb = XZ + (size_t)b * CC * NN;

    __shared__ f16 Asl[128 * APAD];
    __shared__ f16 Bsl[128 * APAD];

    const int tid = threadIdx.x;
    const int wave = tid >> 6, lane = tid & 63;
    const int wr = (wave >> 1) * 64, wc = (wave & 1) * 64;
    const int lrow = lane & 15, lk = (lane >> 4) * 8;

    f32x4 acc[4][4] = {};

    for (int k0 = 0; k0 < CC; k0 += 32) {
#pragma unroll
        for (int i = 0; i < 2; ++i) {
            int idx = tid + 256 * i;
            int r = idx >> 2, ch = idx & 3;
            *(f16x8*)&Asl[r * APAD + ch * 8] =
                *(const f16x8*)&Wb[(size_t)(m0 + r) * CC + k0 + ch * 8];
            *(f16x8*)&Bsl[r * APAD + ch * 8] =
                *(const f16x8*)&Db[(size_t)(n0 + r) * CC + k0 + ch * 8];
        }
        __syncthreads();
        f16x8 af[4], bf[4];
#pragma unroll
        for (int i = 0; i < 4; ++i) {
            af[i] = *(const f16x8*)&Asl[(wr + i * 16 + lrow) * APAD + lk];
            bf[i] = *(const f16x8*)&Bsl[(wc + i * 16 + lrow) * APAD + lk];
        }
#pragma unroll
        for (int i = 0; i < 4; ++i)
#pragma unroll
            for (int j = 0; j < 4; ++j)
                acc[i][j] = __builtin_amdgcn_mfma_f32_16x16x32_f16(
                    af[i], bf[j], acc[i][j], 0, 0, 0);
        __syncthreads();
    }

#pragma unroll
    for (int i = 0; i < 4; ++i) {
#pragma unroll
        for (int q = 0; q < 4; ++q) {
            int o = m0 + wr + i * 16 + (lane >> 4) * 4 + q;
            float al = alpha[o], be = beta[o], bb = bt[o];
            float s1 = 0.f, s2 = 0.f;
#pragma unroll
            for (int j = 0; j < 4; ++j) {
                int n = n0 + wc + j * 16 + lrow;
                float z = al * (acc[i][j][q] + bb) + be;
                Zb[(size_t)o * NN + n] = __float2bfloat16(z);
                s1 += z; s2 += z * z;
            }
#pragma unroll
            for (int d = 1; d < 16; d <<= 1) {
                s1 += __shfl_xor(s1, d);
                s2 += __shfl_xor(s2, d);
            }
            if (lrow == 0) {
                atomicAdd(&bnsum[o], s1);
                atomicAdd(&bnsumsq[o], s2);
            }
        }
    }
}

// ---------------------------------------------------------------------------
// Kernel 7: out = x + relu(gamma*(XZ-mean)*rsqrt(var+eps)+beta)
// ---------------------------------------------------------------------------
__global__ __launch_bounds__(256) void final_kernel(
    const float* __restrict__ x, const bf16* __restrict__ XZ,
    const float* __restrict__ bnsum, const float* __restrict__ bnsumsq,
    const float* __restrict__ gamma, const float* __restrict__ bbeta,
    float* __restrict__ out)
{
    const int i4 = blockIdx.x * 256 + threadIdx.x;
    const int elem = i4 * 4;
    const int c = (elem / NN) % CC;
    const float inv_cnt = 1.f / (float)(BB * NN);
    const float mean = bnsum[c] * inv_cnt;
    const float var  = bnsumsq[c] * inv_cnt - mean * mean;
    const float rs = rsqrtf(var + BN_EPS);
    const float g = gamma[c], bb = bbeta[c];

    ushort4 zu = *(const ushort4*)&XZ[elem];
    float4 xv = *(const float4*)&x[elem];
    float z0 = __uint_as_float((unsigned)zu.x << 16);
    float z1 = __uint_as_float((unsigned)zu.y << 16);
    float z2 = __uint_as_float((unsigned)zu.z << 16);
    float z3 = __uint_as_float((unsigned)zu.w << 16);
    float4 o;
    o.x = xv.x + fmaxf(g * (z0 - mean) * rs + bb, 0.f);
    o.y = xv.y + fmaxf(g * (z1 - mean) * rs + bb, 0.f);
    o.z = xv.z + fmaxf(g * (z2 - mean) * rs + bb, 0.f);
    o.w = xv.w + fmaxf(g * (z3 - mean) * rs + bb, 0.f);
    *(float4*)&out[elem] = o;
}

// ---------------------------------------------------------------------------

extern "C" void kernel_launch(void* const* d_in, const int* in_sizes, int n_in,
                              void* d_out, int out_size, void* d_ws, size_t ws_size,
                              hipStream_t stream) {
    const float* x     = (const float*)d_in[0];
    const float* Wq    = (const float*)d_in[1];
    const float* Wk    = (const float*)d_in[2];
    const float* Wv    = (const float*)d_in[3];
    const float* bv    = (const float*)d_in[4];
    const float* Wt    = (const float*)d_in[5];
    const float* bt    = (const float*)d_in[6];
    const float* gamma = (const float*)d_in[7];
    const float* bbeta = (const float*)d_in[8];
    const float* alpha = (const float*)d_in[9];
    const float* beta  = (const float*)d_in[10];
    float* out = (float*)d_out;

    const size_t BCN = (size_t)BB * CC * NN;   // 4,194,304 elements
    const size_t WSZ = (size_t)4 * CC * CC;    // 262,144

    f16* Whi = (f16*)d_ws;                     // 4 x [C][C] hi
    f16* Wlo = Whi + WSZ;                      // 4 x [C][C] lo
    f16* V16 = Wlo + WSZ;                      // [B][C][N]
    f16* Qhi = V16 + BCN;                      // [B][N][C]
    f16* Khi = Qhi + BCN;                      // [B][N][C]
    float* ATT = (float*)(Khi + BCN);          // [B][N][N] fp32 logits / bf16 attn
    bf16* XZ = (bf16*)(ATT + (size_t)BB * NN * NN);  // [B][C][N] bf16
    float* colsum  = (float*)(XZ + BCN);       // [B][N]
    float* bnsum   = colsum + (size_t)BB * NN; // [C]
    float* bnsumsq = bnsum + CC;               // [C]

    // Xhi/Xlo overlay batch-0's ATT slab (dead by the time energy writes it).
    f16* Xhi = (f16*)ATT;                      // [B][N][C]
    f16* Xlo = Xhi + BCN;                      // [B][N][C]
    f16* Dt16 = Qhi;                           // reuse Qhi after energy

    hipMemsetAsync(colsum, 0, (size_t)(BB * NN + 2 * CC) * sizeof(float), stream);

    prep_w_kernel<<<dim3(4 * CC * CC / 2048), 256, 0, stream>>>(
        Wq, Wk, Wv, Wt, Whi, Wlo);
    prep_x_kernel<<<dim3(NN / 64, CC / 64, BB), 256, 0, stream>>>(x, Xhi, Xlo);
    proj_mfma_kernel<<<dim3(NN / 128, CC / 128, 3 * BB), 256, 0, stream>>>(
        Whi, Wlo, Xhi, Xlo, bv, Qhi, Khi, V16);
    energy_mfma_kernel<<<dim3(NN / 128, NN / 128, BB), 256, 0, stream>>>(
        Qhi, Khi, ATT);
    softmax_kernel<<<dim3(BB * NN), 256, 0, stream>>>(ATT);
    colsum_kernel<<<dim3(NN / 256, 16, BB), 256, 0, stream>>>(ATT, colsum);
    xr_mfma_kernel<<<dim3(NN / 128, CC / 128, BB), 256, 0, stream>>>(
        V16, ATT, colsum, x, Dt16);
    xz_mfma_kernel<<<dim3(NN / 128, CC / 128, BB), 256, 0, stream>>>(
        Whi, Dt16, bt, alpha, beta, XZ, bnsum, bnsumsq);
    final_kernel<<<dim3((int)(BCN / 4 / 256)), 256, 0, stream>>>(
        x, XZ, bnsum, bnsumsq, gamma, bbeta, out);
}

// Round 9
// 251.429 us; speedup vs baseline: 2.8287x; 1.0799x over previous
//
#include <hip/hip_runtime.h>
#include <hip/hip_bf16.h>
#include <math.h>

#define BB 8
#define CC 256
#define NN 2048
static constexpr float BN_EPS = 1e-5f;

typedef _Float16 f16;
typedef f16 f16x2 __attribute__((ext_vector_type(2)));
typedef f16 f16x4 __attribute__((ext_vector_type(4)));
typedef f16 f16x8 __attribute__((ext_vector_type(8)));
typedef float f32x4 __attribute__((ext_vector_type(4)));
typedef __hip_bfloat16 bf16;

#define APAD 40   // f16 row stride (32 data + 8 pad) = 80B, 16B-aligned
#define BPAD 36   // f16 row stride = 72B

// ---------------------------------------------------------------------------
// Prep A: four C x C weight matrices -> hi/lo f16 planes (concatenated).
// ---------------------------------------------------------------------------
__global__ __launch_bounds__(256) void prep_w_kernel(
    const float* __restrict__ Wq, const float* __restrict__ Wk,
    const float* __restrict__ Wv, const float* __restrict__ Wt,
    f16* __restrict__ Whi, f16* __restrict__ Wlo)
{
    int idx = (blockIdx.x * 256 + threadIdx.x) * 8;   // over 4*C*C
    const float* s = (idx < 65536) ? Wq : (idx < 131072) ? Wk
                    : (idx < 196608) ? Wv : Wt;
    int off = idx & 65535;
    float4 a = *(const float4*)&s[off];
    float4 b = *(const float4*)&s[off + 4];
    float v[8] = {a.x, a.y, a.z, a.w, b.x, b.y, b.z, b.w};
    f16x8 h, l;
#pragma unroll
    for (int j = 0; j < 8; ++j) {
        f16 hh = (f16)v[j];
        f16 ll = (f16)(v[j] - (float)hh);
        h[j] = hh;
        l[j] = ll;
    }
    *(f16x8*)&Whi[idx] = h;
    *(f16x8*)&Wlo[idx] = l;
}

// ---------------------------------------------------------------------------
// Prep B: Xhi/Xlo[b][n][c] = split (f16) of x[b][c][n]  (LDS-tiled transpose)
// ---------------------------------------------------------------------------
__global__ __launch_bounds__(256) void prep_x_kernel(
    const float* __restrict__ x, f16* __restrict__ Xhi, f16* __restrict__ Xlo)
{
    const int b = blockIdx.z, c0 = blockIdx.y * 64, n0 = blockIdx.x * 64;
    const float* __restrict__ Xb = x + (size_t)b * CC * NN;
    f16* __restrict__ Oh = Xhi + (size_t)b * NN * CC;
    f16* __restrict__ Ol = Xlo + (size_t)b * NN * CC;
    __shared__ f16 Th[64][72];
    __shared__ f16 Tl[64][72];
    const int tid = threadIdx.x;
    const int r = tid >> 4, c4 = (tid & 15) * 4;
#pragma unroll
    for (int i = 0; i < 4; ++i) {
        int rr = r + i * 16;
        float4 v = *(const float4*)&Xb[(size_t)(c0 + rr) * NN + n0 + c4];
        float vv[4] = {v.x, v.y, v.z, v.w};
#pragma unroll
        for (int j = 0; j < 4; ++j) {
            f16 hh = (f16)vv[j];
            f16 ll = (f16)(vv[j] - (float)hh);
            Th[c4 + j][rr] = hh;
            Tl[c4 + j][rr] = ll;
        }
    }
    __syncthreads();
#pragma unroll
    for (int i = 0; i < 2; ++i) {
        int idx = tid + 256 * i;
        int n = idx >> 3, cg = (idx & 7) * 8;
        *(f16x8*)&Oh[(size_t)(n0 + n) * CC + c0 + cg] = *(f16x8*)&Th[n][cg];
        *(f16x8*)&Ol[(size_t)(n0 + n) * CC + c0 + cg] = *(f16x8*)&Tl[n][cg];
    }
}

// ---------------------------------------------------------------------------
// Kernel 1: projections via split-precision MFMA (hi*hi + hi*lo + lo*hi).
// which 0/1 -> Qhi/Khi f16 [b][n][c] (f16-rounded from fp32-accurate acc);
// which 2 -> V16 f16 [b][c][n] (+bv).
// ---------------------------------------------------------------------------
__global__ __launch_bounds__(256) void proj_mfma_kernel(
    const f16* __restrict__ Whi, const f16* __restrict__ Wlo,
    const f16* __restrict__ Xhi, const f16* __restrict__ Xlo,
    const float* __restrict__ bv,
    f16* __restrict__ Qhi, f16* __restrict__ Khi, f16* __restrict__ V16)
{
    const int which = blockIdx.z >> 3;
    const int b     = blockIdx.z & 7;
    const f16* __restrict__ Wh = Whi + (size_t)which * CC * CC;
    const f16* __restrict__ Wl = Wlo + (size_t)which * CC * CC;
    const f16* __restrict__ Xh = Xhi + (size_t)b * NN * CC;
    const f16* __restrict__ Xl = Xlo + (size_t)b * NN * CC;

    const int m0 = blockIdx.y * 128;   // output channels
    const int n0 = blockIdx.x * 128;   // points

    __shared__ f16 Ah[128 * APAD];
    __shared__ f16 Al[128 * APAD];
    __shared__ f16 Bh[128 * APAD];
    __shared__ f16 Bl[128 * APAD];

    const int tid = threadIdx.x;
    const int wave = tid >> 6, lane = tid & 63;
    const int wr = (wave >> 1) * 64, wc = (wave & 1) * 64;
    const int lrow = lane & 15, lk = (lane >> 4) * 8;

    f32x4 acc[4][4] = {};

    for (int k0 = 0; k0 < CC; k0 += 32) {
#pragma unroll
        for (int i = 0; i < 2; ++i) {
            int idx = tid + 256 * i;
            int r = idx >> 2, ch = idx & 3;
            *(f16x8*)&Ah[r * APAD + ch * 8] =
                *(const f16x8*)&Wh[(size_t)(m0 + r) * CC + k0 + ch * 8];
            *(f16x8*)&Al[r * APAD + ch * 8] =
                *(const f16x8*)&Wl[(size_t)(m0 + r) * CC + k0 + ch * 8];
            *(f16x8*)&Bh[r * APAD + ch * 8] =
                *(const f16x8*)&Xh[(size_t)(n0 + r) * CC + k0 + ch * 8];
            *(f16x8*)&Bl[r * APAD + ch * 8] =
                *(const f16x8*)&Xl[(size_t)(n0 + r) * CC + k0 + ch * 8];
        }
        __syncthreads();
        f16x8 ah[4], al[4], bh[4], bl[4];
#pragma unroll
        for (int i = 0; i < 4; ++i) {
            ah[i] = *(const f16x8*)&Ah[(wr + i * 16 + lrow) * APAD + lk];
            al[i] = *(const f16x8*)&Al[(wr + i * 16 + lrow) * APAD + lk];
            bh[i] = *(const f16x8*)&Bh[(wc + i * 16 + lrow) * APAD + lk];
            bl[i] = *(const f16x8*)&Bl[(wc + i * 16 + lrow) * APAD + lk];
        }
#pragma unroll
        for (int i = 0; i < 4; ++i)
#pragma unroll
            for (int j = 0; j < 4; ++j) {
                acc[i][j] = __builtin_amdgcn_mfma_f32_16x16x32_f16(
                    ah[i], bh[j], acc[i][j], 0, 0, 0);
                acc[i][j] = __builtin_amdgcn_mfma_f32_16x16x32_f16(
                    ah[i], bl[j], acc[i][j], 0, 0, 0);
                acc[i][j] = __builtin_amdgcn_mfma_f32_16x16x32_f16(
                    al[i], bh[j], acc[i][j], 0, 0, 0);
            }
        __syncthreads();
    }

    if (which < 2) {
        f16* __restrict__ Oh = ((which == 0) ? Qhi : Khi) + (size_t)b * NN * CC;
#pragma unroll
        for (int i = 0; i < 4; ++i) {
            int cb = m0 + wr + i * 16 + (lane >> 4) * 4;
#pragma unroll
            for (int j = 0; j < 4; ++j) {
                int n = n0 + wc + j * 16 + lrow;
                f16x4 hv;
#pragma unroll
                for (int q = 0; q < 4; ++q) hv[q] = (f16)acc[i][j][q];
                *(f16x4*)&Oh[(size_t)n * CC + cb] = hv;
            }
        }
    } else {
        f16* __restrict__ Vb = V16 + (size_t)b * CC * NN;
#pragma unroll
        for (int i = 0; i < 4; ++i) {
            int cb = m0 + wr + i * 16 + (lane >> 4) * 4;
#pragma unroll
            for (int q = 0; q < 4; ++q) {
                float bvv = bv[cb + q];
#pragma unroll
                for (int j = 0; j < 4; ++j) {
                    int n = n0 + wc + j * 16 + lrow;
                    Vb[(size_t)(cb + q) * NN + n] = (f16)(acc[i][j][q] + bvv);
                }
            }
        }
    }
}

// ---------------------------------------------------------------------------
// Kernel 2: energy = Qhi . Khi^T -> fp32 logits. LDS-staged hi-only:
// 8 ds_read_b128 feed 16 MFMAs per wave K-step (near-balanced pipes).
// ---------------------------------------------------------------------------
__global__ __launch_bounds__(256) void energy_mfma_kernel(
    const f16* __restrict__ Qhi, const f16* __restrict__ Khi,
    float* __restrict__ ATT)
{
    const int b = blockIdx.z;
    const int n0 = blockIdx.y * 128;
    const int m0 = blockIdx.x * 128;
    const f16* __restrict__ Qh = Qhi + (size_t)b * NN * CC;
    const f16* __restrict__ Kh = Khi + (size_t)b * NN * CC;
    float* __restrict__ Eb = ATT + (size_t)b * NN * NN;

    __shared__ f16 Ah[128 * APAD];
    __shared__ f16 Bh[128 * APAD];

    const int tid = threadIdx.x;
    const int wave = tid >> 6, lane = tid & 63;
    const int wr = (wave >> 1) * 64, wc = (wave & 1) * 64;
    const int lrow = lane & 15, lk = (lane >> 4) * 8;

    f32x4 acc[4][4] = {};

    for (int k0 = 0; k0 < CC; k0 += 32) {
#pragma unroll
        for (int i = 0; i < 2; ++i) {
            int idx = tid + 256 * i;
            int r = idx >> 2, ch = idx & 3;
            *(f16x8*)&Ah[r * APAD + ch * 8] =
                *(const f16x8*)&Qh[(size_t)(n0 + r) * CC + k0 + ch * 8];
            *(f16x8*)&Bh[r * APAD + ch * 8] =
                *(const f16x8*)&Kh[(size_t)(m0 + r) * CC + k0 + ch * 8];
        }
        __syncthreads();
        f16x8 af[4], bf[4];
#pragma unroll
        for (int i = 0; i < 4; ++i) {
            af[i] = *(const f16x8*)&Ah[(wr + i * 16 + lrow) * APAD + lk];
            bf[i] = *(const f16x8*)&Bh[(wc + i * 16 + lrow) * APAD + lk];
        }
#pragma unroll
        for (int i = 0; i < 4; ++i)
#pragma unroll
            for (int j = 0; j < 4; ++j)
                acc[i][j] = __builtin_amdgcn_mfma_f32_16x16x32_f16(
                    af[i], bf[j], acc[i][j], 0, 0, 0);
        __syncthreads();
    }

#pragma unroll
    for (int i = 0; i < 4; ++i)
#pragma unroll
        for (int q = 0; q < 4; ++q) {
            int row = n0 + wr + i * 16 + (lane >> 4) * 4 + q;
#pragma unroll
            for (int j = 0; j < 4; ++j) {
                int col = m0 + wc + j * 16 + lrow;
                Eb[(size_t)row * NN + col] = acc[i][j][q];
            }
        }
}

// ---------------------------------------------------------------------------
// Kernel 3: row softmax; fp32 logits in, normalized bf16 out IN PLACE
// (packed at the row start; bf16 row stride = 2*NN).
// ---------------------------------------------------------------------------
__global__ __launch_bounds__(256) void softmax_kernel(float* __restrict__ ATT)
{
    const size_t row = blockIdx.x;
    float* __restrict__ R = ATT + row * NN;
    const int tid = threadIdx.x;
    const int wave = tid >> 6, lane = tid & 63;

    float e[8];
#pragma unroll
    for (int j = 0; j < 8; ++j) e[j] = R[tid + 256 * j];

    float mx = e[0];
#pragma unroll
    for (int j = 1; j < 8; ++j) mx = fmaxf(mx, e[j]);
#pragma unroll
    for (int s = 1; s < 64; s <<= 1) mx = fmaxf(mx, __shfl_xor(mx, s));

    __shared__ float redm[4];
    if (lane == 0) redm[wave] = mx;
    __syncthreads();
    mx = fmaxf(fmaxf(redm[0], redm[1]), fmaxf(redm[2], redm[3]));

    float s = 0.f;
#pragma unroll
    for (int j = 0; j < 8; ++j) { e[j] = __expf(e[j] - mx); s += e[j]; }
#pragma unroll
    for (int t = 1; t < 64; t <<= 1) s += __shfl_xor(s, t);

    __shared__ float reds[4];
    if (lane == 0) reds[wave] = s;
    __syncthreads();
    s = reds[0] + reds[1] + reds[2] + reds[3];

    const float inv = 1.f / s;
    bf16* __restrict__ R16 = (bf16*)R;
#pragma unroll
    for (int j = 0; j < 8; ++j)
        R16[tid + 256 * j] = __float2bfloat16(e[j] * inv);
}

// ---------------------------------------------------------------------------
// Kernel 4: column sums over bf16 attention
// ---------------------------------------------------------------------------
__global__ __launch_bounds__(256) void colsum_kernel(
    const float* __restrict__ ATT, float* __restrict__ colsum)
{
    const int b = blockIdx.z;
    const int m = blockIdx.x * 256 + threadIdx.x;
    const int n0 = blockIdx.y * 128;
    const bf16* __restrict__ Ab16 = (const bf16*)(ATT + (size_t)b * NN * NN);
    float s = 0.f;
    for (int n = n0; n < n0 + 128; ++n)
        s += __bfloat162float(Ab16[(size_t)n * (2 * NN) + m]);
    atomicAdd(&colsum[b * NN + m], s);
}

// ---------------------------------------------------------------------------
// Kernel 5: x_r = V16 * (ATT_bf16*diag(rcv)); Dt16[n][c] = (f16)(x - x_r)
// f16 conversion happens AFTER the rcv scale (range-safe).
// ---------------------------------------------------------------------------
__global__ __launch_bounds__(256) void xr_mfma_kernel(
    const f16* __restrict__ V16, const float* __restrict__ ATT,
    const float* __restrict__ colsum, const float* __restrict__ x,
    f16* __restrict__ Dt16)
{
    const int b  = blockIdx.z;
    const int c0 = blockIdx.y * 128;
    const int m0 = blockIdx.x * 128;
    const f16* __restrict__ Vb = V16 + (size_t)b * CC * NN;
    const bf16* __restrict__ Ab16 = (const bf16*)(ATT + (size_t)b * NN * NN);
    const float* __restrict__ Xb = x + (size_t)b * CC * NN;
    f16* __restrict__ Db = Dt16 + (size_t)b * NN * CC;

    __shared__ f16 Asl[128 * APAD];
    __shared__ f16 Bsl[128 * BPAD];
    __shared__ float rcv[128];

    const int tid = threadIdx.x;
    if (tid < 128) rcv[tid] = 1.f / (1e-9f + colsum[b * NN + m0 + tid]);
    __syncthreads();

    const int wave = tid >> 6, lane = tid & 63;
    const int wr = (wave >> 1) * 64, wc = (wave & 1) * 64;
    const int lrow = lane & 15, lk = (lane >> 4) * 8;

    f32x4 acc[4][4] = {};

    for (int k0 = 0; k0 < NN; k0 += 32) {
#pragma unroll
        for (int i = 0; i < 2; ++i) {
            int idx = tid + 256 * i;
            int r = idx >> 2, ch = idx & 3;
            *(f16x8*)&Asl[r * APAD + ch * 8] =
                *(const f16x8*)&Vb[(size_t)(c0 + r) * NN + k0 + ch * 8];
        }
#pragma unroll
        for (int i = 0; i < 8; ++i) {
            int idx = tid + 256 * i;
            int m = idx & 127, np = idx >> 7;
            int n = k0 + np * 2;
            float sc = rcv[m];
            float a0 = __bfloat162float(Ab16[(size_t)n * (2 * NN) + m0 + m]) * sc;
            float a1 = __bfloat162float(Ab16[(size_t)(n + 1) * (2 * NN) + m0 + m]) * sc;
            f16x2 p = {(f16)a0, (f16)a1};
            *(f16x2*)&Bsl[m * BPAD + np * 2] = p;
        }
        __syncthreads();
        f16x8 af[4], bf[4];
#pragma unroll
        for (int i = 0; i < 4; ++i) {
            af[i] = *(const f16x8*)&Asl[(wr + i * 16 + lrow) * APAD + lk];
            f16x4 lo = *(const f16x4*)&Bsl[(wc + i * 16 + lrow) * BPAD + lk];
            f16x4 hi = *(const f16x4*)&Bsl[(wc + i * 16 + lrow) * BPAD + lk + 4];
            f16x8 bb;
            bb[0] = lo[0]; bb[1] = lo[1]; bb[2] = lo[2]; bb[3] = lo[3];
            bb[4] = hi[0]; bb[5] = hi[1]; bb[6] = hi[2]; bb[7] = hi[3];
            bf[i] = bb;
        }
#pragma unroll
        for (int i = 0; i < 4; ++i)
#pragma unroll
            for (int j = 0; j < 4; ++j)
                acc[i][j] = __builtin_amdgcn_mfma_f32_16x16x32_f16(
                    af[i], bf[j], acc[i][j], 0, 0, 0);
        __syncthreads();
    }

#pragma unroll
    for (int i = 0; i < 4; ++i) {
        int cb = c0 + wr + i * 16 + (lane >> 4) * 4;
#pragma unroll
        for (int j = 0; j < 4; ++j) {
            int n = m0 + wc + j * 16 + lrow;
            f16x4 dv;
#pragma unroll
            for (int q = 0; q < 4; ++q)
                dv[q] = (f16)(Xb[(size_t)(cb + q) * NN + n] - acc[i][j][q]);
            *(f16x4*)&Db[(size_t)n * CC + cb] = dv;
        }
    }
}

// ---------------------------------------------------------------------------
// Kernel 6: XZ(bf16) = alpha*(Wt*Dt16 + bt) + beta; BN sums from fp32 values.
// ---------------------------------------------------------------------------
__global__ __launch_bounds__(256) void xz_mfma_kernel(
    const f16* __restrict__ Whi, const f16* __restrict__ Dt16,
    const float* __restrict__ bt, const float* __restrict__ alpha,
    const float* __restrict__ beta, bf16* __restrict__ XZ,
    float* __restrict__ bnsum, float* __restrict__ bnsumsq)
{
    const int b = blockIdx.z;
    const int m0 = blockIdx.y * 128;
    const int n0 = blockIdx.x * 128;
    const f16* __restrict__ Wb = Whi + (size_t)3 * CC * CC;   // Wt (hi)
    const f16* __restrict__ Db = Dt16 + (size_t)b * NN * CC;
    bf16* __restrict__ Zb = XZ + (size_t)b * CC * NN;

    __shared__ f16 Asl[128 * APAD];
    __shared__ f16 Bsl[128 * APAD];

    const int tid = threadIdx.x;
    const int wave = tid >> 6, lane = tid & 63;
    const int wr = (wave >> 1) * 64, wc = (wave & 1) * 64;
    const int lrow = lane & 15, lk = (lane >> 4) * 8;

    f32x4 acc[4][4] = {};

    for (int k0 = 0; k0 < CC; k0 += 32) {
#pragma unroll
        for (int i = 0; i < 2; ++i) {
            int idx = tid + 256 * i;
            int r = idx >> 2, ch = idx & 3;
            *(f16x8*)&Asl[r * APAD + ch * 8] =
                *(const f16x8*)&Wb[(size_t)(m0 + r) * CC + k0 + ch * 8];
            *(f16x8*)&Bsl[r * APAD + ch * 8] =
                *(const f16x8*)&Db[(size_t)(n0 + r) * CC + k0 + ch * 8];
        }
        __syncthreads();
        f16x8 af[4], bf[4];
#pragma unroll
        for (int i = 0; i < 4; ++i) {
            af[i] = *(const f16x8*)&Asl[(wr + i * 16 + lrow) * APAD + lk];
            bf[i] = *(const f16x8*)&Bsl[(wc + i * 16 + lrow) * APAD + lk];
        }
#pragma unroll
        for (int i = 0; i < 4; ++i)
#pragma unroll
            for (int j = 0; j < 4; ++j)
                acc[i][j] = __builtin_amdgcn_mfma_f32_16x16x32_f16(
                    af[i], bf[j], acc[i][j], 0, 0, 0);
        __syncthreads();
    }

#pragma unroll
    for (int i = 0; i < 4; ++i) {
#pragma unroll
        for (int q = 0; q < 4; ++q) {
            int o = m0 + wr + i * 16 + (lane >> 4) * 4 + q;
            float al = alpha[o], be = beta[o], bb = bt[o];
            float s1 = 0.f, s2 = 0.f;
#pragma unroll
            for (int j = 0; j < 4; ++j) {
                int n = n0 + wc + j * 16 + lrow;
                float z = al * (acc[i][j][q] + bb) + be;
                Zb[(size_t)o * NN + n] = __float2bfloat16(z);
                s1 += z; s2 += z * z;
            }
#pragma unroll
            for (int d = 1; d < 16; d <<= 1) {
                s1 += __shfl_xor(s1, d);
                s2 += __shfl_xor(s2, d);
            }
            if (lrow == 0) {
                atomicAdd(&bnsum[o], s1);
                atomicAdd(&bnsumsq[o], s2);
            }
        }
    }
}

// ---------------------------------------------------------------------------
// Kernel 7: out = x + relu(gamma*(XZ-mean)*rsqrt(var+eps)+beta)
// ---------------------------------------------------------------------------
__global__ __launch_bounds__(256) void final_kernel(
    const float* __restrict__ x, const bf16* __restrict__ XZ,
    const float* __restrict__ bnsum, const float* __restrict__ bnsumsq,
    const float* __restrict__ gamma, const float* __restrict__ bbeta,
    float* __restrict__ out)
{
    const int i4 = blockIdx.x * 256 + threadIdx.x;
    const int elem = i4 * 4;
    const int c = (elem / NN) % CC;
    const float inv_cnt = 1.f / (float)(BB * NN);
    const float mean = bnsum[c] * inv_cnt;
    const float var  = bnsumsq[c] * inv_cnt - mean * mean;
    const float rs = rsqrtf(var + BN_EPS);
    const float g = gamma[c], bb = bbeta[c];

    ushort4 zu = *(const ushort4*)&XZ[elem];
    float4 xv = *(const float4*)&x[elem];
    float z0 = __uint_as_float((unsigned)zu.x << 16);
    float z1 = __uint_as_float((unsigned)zu.y << 16);
    float z2 = __uint_as_float((unsigned)zu.z << 16);
    float z3 = __uint_as_float((unsigned)zu.w << 16);
    float4 o;
    o.x = xv.x + fmaxf(g * (z0 - mean) * rs + bb, 0.f);
    o.y = xv.y + fmaxf(g * (z1 - mean) * rs + bb, 0.f);
    o.z = xv.z + fmaxf(g * (z2 - mean) * rs + bb, 0.f);
    o.w = xv.w + fmaxf(g * (z3 - mean) * rs + bb, 0.f);
    *(float4*)&out[elem] = o;
}

// ---------------------------------------------------------------------------

extern "C" void kernel_launch(void* const* d_in, const int* in_sizes, int n_in,
                              void* d_out, int out_size, void* d_ws, size_t ws_size,
                              hipStream_t stream) {
    const float* x     = (const float*)d_in[0];
    const float* Wq    = (const float*)d_in[1];
    const float* Wk    = (const float*)d_in[2];
    const float* Wv    = (const float*)d_in[3];
    const float* bv    = (const float*)d_in[4];
    const float* Wt    = (const float*)d_in[5];
    const float* bt    = (const float*)d_in[6];
    const float* gamma = (const float*)d_in[7];
    const float* bbeta = (const float*)d_in[8];
    const float* alpha = (const float*)d_in[9];
    const float* beta  = (const float*)d_in[10];
    float* out = (float*)d_out;

    const size_t BCN = (size_t)BB * CC * NN;   // 4,194,304 elements
    const size_t WSZ = (size_t)4 * CC * CC;    // 262,144

    f16* Whi = (f16*)d_ws;                     // 4 x [C][C] hi
    f16* Wlo = Whi + WSZ;                      // 4 x [C][C] lo
    f16* V16 = Wlo + WSZ;                      // [B][C][N]
    f16* Qhi = V16 + BCN;                      // [B][N][C]
    f16* Khi = Qhi + BCN;                      // [B][N][C]
    float* ATT = (float*)(Khi + BCN);          // [B][N][N] fp32 logits / bf16 attn
    bf16* XZ = (bf16*)(ATT + (size_t)BB * NN * NN);  // [B][C][N] bf16
    float* colsum  = (float*)(XZ + BCN);       // [B][N]
    float* bnsum   = colsum + (size_t)BB * NN; // [C]
    float* bnsumsq = bnsum + CC;               // [C]

    // Xhi/Xlo overlay batch-0's ATT slab (dead by the time energy writes it).
    f16* Xhi = (f16*)ATT;                      // [B][N][C]
    f16* Xlo = Xhi + BCN;                      // [B][N][C]
    f16* Dt16 = Qhi;                           // reuse Qhi after energy

    hipMemsetAsync(colsum, 0, (size_t)(BB * NN + 2 * CC) * sizeof(float), stream);

    prep_w_kernel<<<dim3(4 * CC * CC / 2048), 256, 0, stream>>>(
        Wq, Wk, Wv, Wt, Whi, Wlo);
    prep_x_kernel<<<dim3(NN / 64, CC / 64, BB), 256, 0, stream>>>(x, Xhi, Xlo);
    proj_mfma_kernel<<<dim3(NN / 128, CC / 128, 3 * BB), 256, 0, stream>>>(
        Whi, Wlo, Xhi, Xlo, bv, Qhi, Khi, V16);
    energy_mfma_kernel<<<dim3(NN / 128, NN / 128, BB), 256, 0, stream>>>(
        Qhi, Khi, ATT);
    softmax_kernel<<<dim3(BB * NN), 256, 0, stream>>>(ATT);
    colsum_kernel<<<dim3(NN / 256, 16, BB), 256, 0, stream>>>(ATT, colsum);
    xr_mfma_kernel<<<dim3(NN / 128, CC / 128, BB), 256, 0, stream>>>(
        V16, ATT, colsum, x, Dt16);
    xz_mfma_kernel<<<dim3(NN / 128, CC / 128, BB), 256, 0, stream>>>(
        Whi, Dt16, bt, alpha, beta, XZ, bnsum, bnsumsq);
    final_kernel<<<dim3((int)(BCN / 4 / 256)), 256, 0, stream>>>(
        x, XZ, bnsum, bnsumsq, gamma, bbeta, out);
}

// Round 10
// 245.654 us; speedup vs baseline: 2.8952x; 1.0235x over previous
//
#include <hip/hip_runtime.h>
#include <hip/hip_bf16.h>
#include <math.h>

#define BB 8
#define CC 256
#define NN 2048
static constexpr float BN_EPS = 1e-5f;

typedef _Float16 f16;
typedef f16 f16x4 __attribute__((ext_vector_type(4)));
typedef f16 f16x8 __attribute__((ext_vector_type(8)));
typedef float f32x4 __attribute__((ext_vector_type(4)));
typedef short s16x8 __attribute__((ext_vector_type(8)));     // 8 bf16 (MFMA operand)
typedef unsigned short u16x8 __attribute__((ext_vector_type(8)));  // 16B raw
typedef __hip_bfloat16 bf16;

#define APAD 40   // 16-bit-elem row stride (32 data + 8 pad) = 80B, 16B-aligned

// ---------------------------------------------------------------------------
// Prep A: four C x C weight matrices -> hi/lo f16 planes (concatenated).
// ---------------------------------------------------------------------------
__global__ __launch_bounds__(256) void prep_w_kernel(
    const float* __restrict__ Wq, const float* __restrict__ Wk,
    const float* __restrict__ Wv, const float* __restrict__ Wt,
    f16* __restrict__ Whi, f16* __restrict__ Wlo)
{
    int idx = (blockIdx.x * 256 + threadIdx.x) * 8;   // over 4*C*C
    const float* s = (idx < 65536) ? Wq : (idx < 131072) ? Wk
                    : (idx < 196608) ? Wv : Wt;
    int off = idx & 65535;
    float4 a = *(const float4*)&s[off];
    float4 b = *(const float4*)&s[off + 4];
    float v[8] = {a.x, a.y, a.z, a.w, b.x, b.y, b.z, b.w};
    f16x8 h, l;
#pragma unroll
    for (int j = 0; j < 8; ++j) {
        f16 hh = (f16)v[j];
        f16 ll = (f16)(v[j] - (float)hh);
        h[j] = hh;
        l[j] = ll;
    }
    *(f16x8*)&Whi[idx] = h;
    *(f16x8*)&Wlo[idx] = l;
}

// ---------------------------------------------------------------------------
// Prep B: Xhi/Xlo[b][n][c] = split (f16) of x[b][c][n]  (LDS-tiled transpose)
// ---------------------------------------------------------------------------
__global__ __launch_bounds__(256) void prep_x_kernel(
    const float* __restrict__ x, f16* __restrict__ Xhi, f16* __restrict__ Xlo)
{
    const int b = blockIdx.z, c0 = blockIdx.y * 64, n0 = blockIdx.x * 64;
    const float* __restrict__ Xb = x + (size_t)b * CC * NN;
    f16* __restrict__ Oh = Xhi + (size_t)b * NN * CC;
    f16* __restrict__ Ol = Xlo + (size_t)b * NN * CC;
    __shared__ f16 Th[64][72];
    __shared__ f16 Tl[64][72];
    const int tid = threadIdx.x;
    const int r = tid >> 4, c4 = (tid & 15) * 4;
#pragma unroll
    for (int i = 0; i < 4; ++i) {
        int rr = r + i * 16;
        float4 v = *(const float4*)&Xb[(size_t)(c0 + rr) * NN + n0 + c4];
        float vv[4] = {v.x, v.y, v.z, v.w};
#pragma unroll
        for (int j = 0; j < 4; ++j) {
            f16 hh = (f16)vv[j];
            f16 ll = (f16)(vv[j] - (float)hh);
            Th[c4 + j][rr] = hh;
            Tl[c4 + j][rr] = ll;
        }
    }
    __syncthreads();
#pragma unroll
    for (int i = 0; i < 2; ++i) {
        int idx = tid + 256 * i;
        int n = idx >> 3, cg = (idx & 7) * 8;
        *(f16x8*)&Oh[(size_t)(n0 + n) * CC + c0 + cg] = *(f16x8*)&Th[n][cg];
        *(f16x8*)&Ol[(size_t)(n0 + n) * CC + c0 + cg] = *(f16x8*)&Tl[n][cg];
    }
}

// ---------------------------------------------------------------------------
// Kernel 1: projections via split-precision MFMA (hi*hi + hi*lo + lo*hi).
// which 0/1 -> Qhi/Khi f16 [b][n][c]; which 2 -> Vb16 bf16 [b][c][n] (+bv).
// ---------------------------------------------------------------------------
__global__ __launch_bounds__(256) void proj_mfma_kernel(
    const f16* __restrict__ Whi, const f16* __restrict__ Wlo,
    const f16* __restrict__ Xhi, const f16* __restrict__ Xlo,
    const float* __restrict__ bv,
    f16* __restrict__ Qhi, f16* __restrict__ Khi, bf16* __restrict__ Vb16)
{
    const int which = blockIdx.z >> 3;
    const int b     = blockIdx.z & 7;
    const f16* __restrict__ Wh = Whi + (size_t)which * CC * CC;
    const f16* __restrict__ Wl = Wlo + (size_t)which * CC * CC;
    const f16* __restrict__ Xh = Xhi + (size_t)b * NN * CC;
    const f16* __restrict__ Xl = Xlo + (size_t)b * NN * CC;

    const int m0 = blockIdx.y * 128;   // output channels
    const int n0 = blockIdx.x * 128;   // points

    __shared__ f16 Ah[128 * APAD];
    __shared__ f16 Al[128 * APAD];
    __shared__ f16 Bh[128 * APAD];
    __shared__ f16 Bl[128 * APAD];

    const int tid = threadIdx.x;
    const int wave = tid >> 6, lane = tid & 63;
    const int wr = (wave >> 1) * 64, wc = (wave & 1) * 64;
    const int lrow = lane & 15, lk = (lane >> 4) * 8;

    f32x4 acc[4][4] = {};

    for (int k0 = 0; k0 < CC; k0 += 32) {
#pragma unroll
        for (int i = 0; i < 2; ++i) {
            int idx = tid + 256 * i;
            int r = idx >> 2, ch = idx & 3;
            *(f16x8*)&Ah[r * APAD + ch * 8] =
                *(const f16x8*)&Wh[(size_t)(m0 + r) * CC + k0 + ch * 8];
            *(f16x8*)&Al[r * APAD + ch * 8] =
                *(const f16x8*)&Wl[(size_t)(m0 + r) * CC + k0 + ch * 8];
            *(f16x8*)&Bh[r * APAD + ch * 8] =
                *(const f16x8*)&Xh[(size_t)(n0 + r) * CC + k0 + ch * 8];
            *(f16x8*)&Bl[r * APAD + ch * 8] =
                *(const f16x8*)&Xl[(size_t)(n0 + r) * CC + k0 + ch * 8];
        }
        __syncthreads();
        f16x8 ah[4], al[4], bh[4], bl[4];
#pragma unroll
        for (int i = 0; i < 4; ++i) {
            ah[i] = *(const f16x8*)&Ah[(wr + i * 16 + lrow) * APAD + lk];
            al[i] = *(const f16x8*)&Al[(wr + i * 16 + lrow) * APAD + lk];
            bh[i] = *(const f16x8*)&Bh[(wc + i * 16 + lrow) * APAD + lk];
            bl[i] = *(const f16x8*)&Bl[(wc + i * 16 + lrow) * APAD + lk];
        }
#pragma unroll
        for (int i = 0; i < 4; ++i)
#pragma unroll
            for (int j = 0; j < 4; ++j) {
                acc[i][j] = __builtin_amdgcn_mfma_f32_16x16x32_f16(
                    ah[i], bh[j], acc[i][j], 0, 0, 0);
                acc[i][j] = __builtin_amdgcn_mfma_f32_16x16x32_f16(
                    ah[i], bl[j], acc[i][j], 0, 0, 0);
                acc[i][j] = __builtin_amdgcn_mfma_f32_16x16x32_f16(
                    al[i], bh[j], acc[i][j], 0, 0, 0);
            }
        __syncthreads();
    }

    if (which < 2) {
        f16* __restrict__ Oh = ((which == 0) ? Qhi : Khi) + (size_t)b * NN * CC;
#pragma unroll
        for (int i = 0; i < 4; ++i) {
            int cb = m0 + wr + i * 16 + (lane >> 4) * 4;
#pragma unroll
            for (int j = 0; j < 4; ++j) {
                int n = n0 + wc + j * 16 + lrow;
                f16x4 hv;
#pragma unroll
                for (int q = 0; q < 4; ++q) hv[q] = (f16)acc[i][j][q];
                *(f16x4*)&Oh[(size_t)n * CC + cb] = hv;
            }
        }
    } else {
        bf16* __restrict__ Vb = Vb16 + (size_t)b * CC * NN;
#pragma unroll
        for (int i = 0; i < 4; ++i) {
            int cb = m0 + wr + i * 16 + (lane >> 4) * 4;
#pragma unroll
            for (int q = 0; q < 4; ++q) {
                float bvv = bv[cb + q];
#pragma unroll
                for (int j = 0; j < 4; ++j) {
                    int n = n0 + wc + j * 16 + lrow;
                    Vb[(size_t)(cb + q) * NN + n] = __float2bfloat16(acc[i][j][q] + bvv);
                }
            }
        }
    }
}

// ---------------------------------------------------------------------------
// Kernel 2: energy = Qhi . Khi^T -> fp32 logits (LDS-staged hi-only).
// ---------------------------------------------------------------------------
__global__ __launch_bounds__(256) void energy_mfma_kernel(
    const f16* __restrict__ Qhi, const f16* __restrict__ Khi,
    float* __restrict__ ATT)
{
    const int b = blockIdx.z;
    const int n0 = blockIdx.y * 128;
    const int m0 = blockIdx.x * 128;
    const f16* __restrict__ Qh = Qhi + (size_t)b * NN * CC;
    const f16* __restrict__ Kh = Khi + (size_t)b * NN * CC;
    float* __restrict__ Eb = ATT + (size_t)b * NN * NN;

    __shared__ f16 Ah[128 * APAD];
    __shared__ f16 Bh[128 * APAD];

    const int tid = threadIdx.x;
    const int wave = tid >> 6, lane = tid & 63;
    const int wr = (wave >> 1) * 64, wc = (wave & 1) * 64;
    const int lrow = lane & 15, lk = (lane >> 4) * 8;

    f32x4 acc[4][4] = {};

    for (int k0 = 0; k0 < CC; k0 += 32) {
#pragma unroll
        for (int i = 0; i < 2; ++i) {
            int idx = tid + 256 * i;
            int r = idx >> 2, ch = idx & 3;
            *(f16x8*)&Ah[r * APAD + ch * 8] =
                *(const f16x8*)&Qh[(size_t)(n0 + r) * CC + k0 + ch * 8];
            *(f16x8*)&Bh[r * APAD + ch * 8] =
                *(const f16x8*)&Kh[(size_t)(m0 + r) * CC + k0 + ch * 8];
        }
        __syncthreads();
        f16x8 af[4], bf[4];
#pragma unroll
        for (int i = 0; i < 4; ++i) {
            af[i] = *(const f16x8*)&Ah[(wr + i * 16 + lrow) * APAD + lk];
            bf[i] = *(const f16x8*)&Bh[(wc + i * 16 + lrow) * APAD + lk];
        }
#pragma unroll
        for (int i = 0; i < 4; ++i)
#pragma unroll
            for (int j = 0; j < 4; ++j)
                acc[i][j] = __builtin_amdgcn_mfma_f32_16x16x32_f16(
                    af[i], bf[j], acc[i][j], 0, 0, 0);
        __syncthreads();
    }

#pragma unroll
    for (int i = 0; i < 4; ++i)
#pragma unroll
        for (int q = 0; q < 4; ++q) {
            int row = n0 + wr + i * 16 + (lane >> 4) * 4 + q;
#pragma unroll
            for (int j = 0; j < 4; ++j) {
                int col = m0 + wc + j * 16 + lrow;
                Eb[(size_t)row * NN + col] = acc[i][j][q];
            }
        }
}

// ---------------------------------------------------------------------------
// Kernel 3: row softmax; fp32 logits in, normalized bf16 out IN PLACE
// (packed at the row start; bf16 row stride = 2*NN).
// ---------------------------------------------------------------------------
__global__ __launch_bounds__(256) void softmax_kernel(float* __restrict__ ATT)
{
    const size_t row = blockIdx.x;
    float* __restrict__ R = ATT + row * NN;
    const int tid = threadIdx.x;
    const int wave = tid >> 6, lane = tid & 63;

    float e[8];
#pragma unroll
    for (int j = 0; j < 8; ++j) e[j] = R[tid + 256 * j];

    float mx = e[0];
#pragma unroll
    for (int j = 1; j < 8; ++j) mx = fmaxf(mx, e[j]);
#pragma unroll
    for (int s = 1; s < 64; s <<= 1) mx = fmaxf(mx, __shfl_xor(mx, s));

    __shared__ float redm[4];
    if (lane == 0) redm[wave] = mx;
    __syncthreads();
    mx = fmaxf(fmaxf(redm[0], redm[1]), fmaxf(redm[2], redm[3]));

    float s = 0.f;
#pragma unroll
    for (int j = 0; j < 8; ++j) { e[j] = __expf(e[j] - mx); s += e[j]; }
#pragma unroll
    for (int t = 1; t < 64; t <<= 1) s += __shfl_xor(s, t);

    __shared__ float reds[4];
    if (lane == 0) reds[wave] = s;
    __syncthreads();
    s = reds[0] + reds[1] + reds[2] + reds[3];

    const float inv = 1.f / s;
    bf16* __restrict__ R16 = (bf16*)R;
#pragma unroll
    for (int j = 0; j < 8; ++j)
        R16[tid + 256 * j] = __float2bfloat16(e[j] * inv);
}

// ---------------------------------------------------------------------------
// Kernel 4: fused column-sum + transpose. Reads bf16 attn rows [n][m],
// atomically accumulates column sums, and writes A^T bf16 [m][n] into the
// UNUSED second half of each fp32 ATT row (disjoint byte ranges, any order).
// ---------------------------------------------------------------------------
__global__ __launch_bounds__(256) void colsum_tr_kernel(
    float* __restrict__ ATT, float* __restrict__ colsum)
{
    const int b = blockIdx.z;
    const int n0 = blockIdx.x * 64;
    const int m0 = blockIdx.y * 64;
    bf16* __restrict__ A16 = (bf16*)(ATT + (size_t)b * NN * NN);

    __shared__ bf16 T[64][72];   // T[m][n], row stride 144B (16B-aligned)
    const int tid = threadIdx.x;

#pragma unroll
    for (int i = 0; i < 2; ++i) {
        int idx = tid + 256 * i;
        int r = idx >> 3, ch = idx & 7;    // row n0+r, m-chunk ch*8
        u16x8 v = *(const u16x8*)&A16[(size_t)(n0 + r) * (2 * NN) + m0 + ch * 8];
#pragma unroll
        for (int j = 0; j < 8; ++j) T[ch * 8 + j][r] = ((bf16*)&v)[j];
    }
    __syncthreads();

    // column-sum partials: 4 threads per m-row, each sums 16 n's
    {
        int m = tid >> 2, q = tid & 3;
        float s = 0.f;
#pragma unroll
        for (int j = 0; j < 16; ++j)
            s += __bfloat162float(T[m][q * 16 + j]);
        s += __shfl_xor(s, 1);
        s += __shfl_xor(s, 2);
        if (q == 0) atomicAdd(&colsum[b * NN + m0 + m], s);
    }

    // transposed write: row m at bf16 offset m*2NN + NN (+ n)
#pragma unroll
    for (int i = 0; i < 2; ++i) {
        int idx = tid + 256 * i;
        int mr = idx >> 3, ch = idx & 7;
        u16x8 w = *(const u16x8*)&T[mr][ch * 8];
        *(u16x8*)&A16[(size_t)(m0 + mr) * (2 * NN) + NN + n0 + ch * 8] = w;
    }
}

// ---------------------------------------------------------------------------
// Kernel 5: x_r_raw = V . A^T (bf16 MFMA, linear staging both sides);
// epilogue applies rcv[m] (rcv commutes out of the GEMM) and writes
// Dt16[n][c] = (f16)(x - x_r_raw*rcv).
// ---------------------------------------------------------------------------
__global__ __launch_bounds__(256) void xr_mfma_kernel(
    const bf16* __restrict__ Vb16, const float* __restrict__ ATT,
    const float* __restrict__ colsum, const float* __restrict__ x,
    f16* __restrict__ Dt16)
{
    const int b  = blockIdx.z;
    const int c0 = blockIdx.y * 128;
    const int m0 = blockIdx.x * 128;
    const bf16* __restrict__ Vb = Vb16 + (size_t)b * CC * NN;
    const bf16* __restrict__ A16 = (const bf16*)(ATT + (size_t)b * NN * NN);
    const float* __restrict__ Xb = x + (size_t)b * CC * NN;
    f16* __restrict__ Db = Dt16 + (size_t)b * NN * CC;

    __shared__ bf16 Asl[128 * APAD];
    __shared__ bf16 Bsl[128 * APAD];
    __shared__ float rcvL[128];

    const int tid = threadIdx.x;
    if (tid < 128) rcvL[tid] = 1.f / (1e-9f + colsum[b * NN + m0 + tid]);

    const int wave = tid >> 6, lane = tid & 63;
    const int wr = (wave >> 1) * 64, wc = (wave & 1) * 64;
    const int lrow = lane & 15, lk = (lane >> 4) * 8;

    f32x4 acc[4][4] = {};

    for (int k0 = 0; k0 < NN; k0 += 32) {
#pragma unroll
        for (int i = 0; i < 2; ++i) {
            int idx = tid + 256 * i;
            int r = idx >> 2, ch = idx & 3;
            *(u16x8*)&Asl[r * APAD + ch * 8] =
                *(const u16x8*)&Vb[(size_t)(c0 + r) * NN + k0 + ch * 8];
            // A^T row m at bf16 offset m*2NN + NN
            *(u16x8*)&Bsl[r * APAD + ch * 8] =
                *(const u16x8*)&A16[(size_t)(m0 + r) * (2 * NN) + NN + k0 + ch * 8];
        }
        __syncthreads();
        s16x8 af[4], bf[4];
#pragma unroll
        for (int i = 0; i < 4; ++i) {
            af[i] = *(const s16x8*)&Asl[(wr + i * 16 + lrow) * APAD + lk];
            bf[i] = *(const s16x8*)&Bsl[(wc + i * 16 + lrow) * APAD + lk];
        }
#pragma unroll
        for (int i = 0; i < 4; ++i)
#pragma unroll
            for (int j = 0; j < 4; ++j)
                acc[i][j] = __builtin_amdgcn_mfma_f32_16x16x32_bf16(
                    af[i], bf[j], acc[i][j], 0, 0, 0);
        __syncthreads();
    }

#pragma unroll
    for (int i = 0; i < 4; ++i) {
        int cb = c0 + wr + i * 16 + (lane >> 4) * 4;
#pragma unroll
        for (int j = 0; j < 4; ++j) {
            int lcol = wc + j * 16 + lrow;
            int n = m0 + lcol;
            float rc = rcvL[lcol];
            f16x4 dv;
#pragma unroll
            for (int q = 0; q < 4; ++q)
                dv[q] = (f16)(Xb[(size_t)(cb + q) * NN + n] - acc[i][j][q] * rc);
            *(f16x4*)&Db[(size_t)n * CC + cb] = dv;
        }
    }
}

// ---------------------------------------------------------------------------
// Kernel 6: XZ(bf16) = alpha*(Wt*Dt16 + bt) + beta; BN sums from fp32 values.
// ---------------------------------------------------------------------------
__global__ __launch_bounds__(256) void xz_mfma_kernel(
    const f16* __restrict__ Whi, const f16* __restrict__ Dt16,
    const float* __restrict__ bt, const float* __restrict__ alpha,
    const float* __restrict__ beta, bf16* __restrict__ XZ,
    float* __restrict__ bnsum, float* __restrict__ bnsumsq)
{
    const int b = blockIdx.z;
    const int m0 = blockIdx.y * 128;
    const int n0 = blockIdx.x * 128;
    const f16* __restrict__ Wb = Whi + (size_t)3 * CC * CC;   // Wt (hi)
    const f16* __restrict__ Db = Dt16 + (size_t)b * NN * CC;
    bf16* __restrict__ Zb = XZ + (size_t)b * CC * NN;

    __shared__ f16 Asl[128 * APAD];
    __shared__ f16 Bsl[128 * APAD];

    const int tid = threadIdx.x;
    const int wave = tid >> 6, lane = tid & 63;
    const int wr = (wave >> 1) * 64, wc = (wave & 1) * 64;
    const int lrow = lane & 15, lk = (lane >> 4) * 8;

    f32x4 acc[4][4] = {};

    for (int k0 = 0; k0 < CC; k0 += 32) {
#pragma unroll
        for (int i = 0; i < 2; ++i) {
            int idx = tid + 256 * i;
            int r = idx >> 2, ch = idx & 3;
            *(f16x8*)&Asl[r * APAD + ch * 8] =
                *(const f16x8*)&Wb[(size_t)(m0 + r) * CC + k0 + ch * 8];
            *(f16x8*)&Bsl[r * APAD + ch * 8] =
                *(const f16x8*)&Db[(size_t)(n0 + r) * CC + k0 + ch * 8];
        }
        __syncthreads();
        f16x8 af[4], bf[4];
#pragma unroll
        for (int i = 0; i < 4; ++i) {
            af[i] = *(const f16x8*)&Asl[(wr + i * 16 + lrow) * APAD + lk];
            bf[i] = *(const f16x8*)&Bsl[(wc + i * 16 + lrow) * APAD + lk];
        }
#pragma unroll
        for (int i = 0; i < 4; ++i)
#pragma unroll
            for (int j = 0; j < 4; ++j)
                acc[i][j] = __builtin_amdgcn_mfma_f32_16x16x32_f16(
                    af[i], bf[j], acc[i][j], 0, 0, 0);
        __syncthreads();
    }

#pragma unroll
    for (int i = 0; i < 4; ++i) {
#pragma unroll
        for (int q = 0; q < 4; ++q) {
            int o = m0 + wr + i * 16 + (lane >> 4) * 4 + q;
            float al = alpha[o], be = beta[o], bb = bt[o];
            float s1 = 0.f, s2 = 0.f;
#pragma unroll
            for (int j = 0; j < 4; ++j) {
                int n = n0 + wc + j * 16 + lrow;
                float z = al * (acc[i][j][q] + bb) + be;
                Zb[(size_t)o * NN + n] = __float2bfloat16(z);
                s1 += z; s2 += z * z;
            }
#pragma unroll
            for (int d = 1; d < 16; d <<= 1) {
                s1 += __shfl_xor(s1, d);
                s2 += __shfl_xor(s2, d);
            }
            if (lrow == 0) {
                atomicAdd(&bnsum[o], s1);
                atomicAdd(&bnsumsq[o], s2);
            }
        }
    }
}

// ---------------------------------------------------------------------------
// Kernel 7: out = x + relu(gamma*(XZ-mean)*rsqrt(var+eps)+beta)
// ---------------------------------------------------------------------------
__global__ __launch_bounds__(256) void final_kernel(
    const float* __restrict__ x, const bf16* __restrict__ XZ,
    const float* __restrict__ bnsum, const float* __restrict__ bnsumsq,
    const float* __restrict__ gamma, const float* __restrict__ bbeta,
    float* __restrict__ out)
{
    const int i4 = blockIdx.x * 256 + threadIdx.x;
    const int elem = i4 * 4;
    const int c = (elem / NN) % CC;
    const float inv_cnt = 1.f / (float)(BB * NN);
    const float mean = bnsum[c] * inv_cnt;
    const float var  = bnsumsq[c] * inv_cnt - mean * mean;
    const float rs = rsqrtf(var + BN_EPS);
    const float g = gamma[c], bb = bbeta[c];

    ushort4 zu = *(const ushort4*)&XZ[elem];
    float4 xv = *(const float4*)&x[elem];
    float z0 = __uint_as_float((unsigned)zu.x << 16);
    float z1 = __uint_as_float((unsigned)zu.y << 16);
    float z2 = __uint_as_float((unsigned)zu.z << 16);
    float z3 = __uint_as_float((unsigned)zu.w << 16);
    float4 o;
    o.x = xv.x + fmaxf(g * (z0 - mean) * rs + bb, 0.f);
    o.y = xv.y + fmaxf(g * (z1 - mean) * rs + bb, 0.f);
    o.z = xv.z + fmaxf(g * (z2 - mean) * rs + bb, 0.f);
    o.w = xv.w + fmaxf(g * (z3 - mean) * rs + bb, 0.f);
    *(float4*)&out[elem] = o;
}

// ---------------------------------------------------------------------------

extern "C" void kernel_launch(void* const* d_in, const int* in_sizes, int n_in,
                              void* d_out, int out_size, void* d_ws, size_t ws_size,
                              hipStream_t stream) {
    const float* x     = (const float*)d_in[0];
    const float* Wq    = (const float*)d_in[1];
    const float* Wk    = (const float*)d_in[2];
    const float* Wv    = (const float*)d_in[3];
    const float* bv    = (const float*)d_in[4];
    const float* Wt    = (const float*)d_in[5];
    const float* bt    = (const float*)d_in[6];
    const float* gamma = (const float*)d_in[7];
    const float* bbeta = (const float*)d_in[8];
    const float* alpha = (const float*)d_in[9];
    const float* beta  = (const float*)d_in[10];
    float* out = (float*)d_out;

    const size_t BCN = (size_t)BB * CC * NN;   // 4,194,304 elements
    const size_t WSZ = (size_t)4 * CC * CC;    // 262,144

    f16* Whi = (f16*)d_ws;                     // 4 x [C][C] hi
    f16* Wlo = Whi + WSZ;                      // 4 x [C][C] lo
    bf16* Vb16 = (bf16*)(Wlo + WSZ);           // [B][C][N] bf16
    f16* Qhi = (f16*)(Vb16 + BCN);             // [B][N][C]
    f16* Khi = Qhi + BCN;                      // [B][N][C]
    float* ATT = (float*)(Khi + BCN);          // [B][N][N]: bf16 attn rows (1st half) + bf16 attn^T rows (2nd half)
    bf16* XZ = (bf16*)(ATT + (size_t)BB * NN * NN);  // [B][C][N] bf16
    float* colsum  = (float*)(XZ + BCN);       // [B][N]
    float* bnsum   = colsum + (size_t)BB * NN; // [C]
    float* bnsumsq = bnsum + CC;               // [C]

    // Xhi/Xlo overlay batch-0's ATT slab (dead by the time energy writes it).
    f16* Xhi = (f16*)ATT;                      // [B][N][C]
    f16* Xlo = Xhi + BCN;                      // [B][N][C]
    f16* Dt16 = Qhi;                           // reuse Qhi after energy

    hipMemsetAsync(colsum, 0, (size_t)(BB * NN + 2 * CC) * sizeof(float), stream);

    prep_w_kernel<<<dim3(4 * CC * CC / 2048), 256, 0, stream>>>(
        Wq, Wk, Wv, Wt, Whi, Wlo);
    prep_x_kernel<<<dim3(NN / 64, CC / 64, BB), 256, 0, stream>>>(x, Xhi, Xlo);
    proj_mfma_kernel<<<dim3(NN / 128, CC / 128, 3 * BB), 256, 0, stream>>>(
        Whi, Wlo, Xhi, Xlo, bv, Qhi, Khi, Vb16);
    energy_mfma_kernel<<<dim3(NN / 128, NN / 128, BB), 256, 0, stream>>>(
        Qhi, Khi, ATT);
    softmax_kernel<<<dim3(BB * NN), 256, 0, stream>>>(ATT);
    colsum_tr_kernel<<<dim3(NN / 64, NN / 64, BB), 256, 0, stream>>>(ATT, colsum);
    xr_mfma_kernel<<<dim3(NN / 128, CC / 128, BB), 256, 0, stream>>>(
        Vb16, ATT, colsum, x, Dt16);
    xz_mfma_kernel<<<dim3(NN / 128, CC / 128, BB), 256, 0, stream>>>(
        Whi, Dt16, bt, alpha, beta, XZ, bnsum, bnsumsq);
    final_kernel<<<dim3((int)(BCN / 4 / 256)), 256, 0, stream>>>(
        x, XZ, bnsum, bnsumsq, gamma, bbeta, out);
}